// Round 2
// baseline (371.727 us; speedup 1.0000x reference)
//
#include <hip/hip_runtime.h>

#define DM 1024
#define H_ 16
#define DH 64
#define B_ 8
#define S_ 1024

typedef _Float16 half8 __attribute__((ext_vector_type(8)));
typedef _Float16 half4 __attribute__((ext_vector_type(4)));
typedef float f32x4 __attribute__((ext_vector_type(4)));

// ---------------------------------------------------------------------------
// Pack weights. W_Q/W_K -> fp16 hi/lo split pairs in B^T [n=h*64+l][k] layout.
// W_V -> fp16 B^T. W_out [1024][1024] already [n][k] -> plain fp16.
// ---------------------------------------------------------------------------
__global__ __launch_bounds__(256) void pack_k(
    const float* __restrict__ WQ, const float* __restrict__ WK,
    const float* __restrict__ WV, const float* __restrict__ WO,
    _Float16* __restrict__ wqh, _Float16* __restrict__ wql,
    _Float16* __restrict__ wkh, _Float16* __restrict__ wkl,
    _Float16* __restrict__ wv,  _Float16* __restrict__ wo)
{
    int idx = blockIdx.x * 256 + threadIdx.x;      // 0 .. 1M-1 (input-linear)
    int h  = idx >> 16;
    int kk = (idx >> 6) & 1023;
    int ll = idx & 63;
    int o = (h * 64 + ll) * DM + kk;               // [n][k]
    float q = WQ[idx];
    _Float16 qh = (_Float16)q;
    wqh[o] = qh; wql[o] = (_Float16)(q - (float)qh);
    float k = WK[idx];
    _Float16 kh = (_Float16)k;
    wkh[o] = kh; wkl[o] = (_Float16)(k - (float)kh);
    wv[o] = (_Float16)WV[idx];
    wo[idx] = (_Float16)WO[idx];
}

// ---------------------------------------------------------------------------
// Split-precision GEMM (Q,K projections): C[M=8192,N=1024] = A[M,K] * Bt[N,K]^T
// A f32, split hi/lo during staging; B pre-split. 3 MFMAs per frag pair
// (hh + hl + lh) -> ~fp29 product accuracy, fp32 accumulate.
// Epilogue stores C as fp16 hi/lo pair (rel err ~2^-22).
// z: 0 -> Q set, 1 -> K set.
// ---------------------------------------------------------------------------
__global__ __launch_bounds__(256) void gemm_split_k(
    const float* __restrict__ A0, const float* __restrict__ A1,
    const _Float16* __restrict__ Bh0, const _Float16* __restrict__ Bl0,
    const _Float16* __restrict__ Bh1, const _Float16* __restrict__ Bl1,
    _Float16* __restrict__ Chi0, _Float16* __restrict__ Clo0,
    _Float16* __restrict__ Chi1, _Float16* __restrict__ Clo1)
{
    const int z = blockIdx.z;
    const float* A = z ? A1 : A0;
    const _Float16* Bh = z ? Bh1 : Bh0;
    const _Float16* Bl = z ? Bl1 : Bl0;
    _Float16* Chi = z ? Chi1 : Chi0;
    _Float16* Clo = z ? Clo1 : Clo0;

    __shared__ __align__(16) _Float16 Ah[128][72];
    __shared__ __align__(16) _Float16 Al[128][72];
    __shared__ __align__(16) _Float16 Bhs[128][72];
    __shared__ __align__(16) _Float16 Bls[128][72];

    const int t = threadIdx.x;
    const int lane = t & 63;
    const int w = t >> 6;
    const int wm = (w >> 1) * 64;
    const int wn = (w & 1) * 64;
    const int l15 = lane & 15;
    const int l4g = lane >> 4;

    const int bm = blockIdx.y * 128;
    const int bn = blockIdx.x * 128;

    f32x4 acc[4][4] = {};

    for (int kt = 0; kt < DM; kt += 64) {
        #pragma unroll
        for (int i = 0; i < 8; ++i) {
            int f = t + 256 * i;               // 0..2047
            int row = f >> 4;
            int c4 = f & 15;
            float4 v = *(const float4*)(A + (size_t)(bm + row) * DM + kt + c4 * 4);
            half4 hv, lv;
            hv[0] = (_Float16)v.x; lv[0] = (_Float16)(v.x - (float)hv[0]);
            hv[1] = (_Float16)v.y; lv[1] = (_Float16)(v.y - (float)hv[1]);
            hv[2] = (_Float16)v.z; lv[2] = (_Float16)(v.z - (float)hv[2]);
            hv[3] = (_Float16)v.w; lv[3] = (_Float16)(v.w - (float)hv[3]);
            *(half4*)&Ah[row][c4 * 4] = hv;
            *(half4*)&Al[row][c4 * 4] = lv;
        }
        #pragma unroll
        for (int i = 0; i < 4; ++i) {
            int f = t + 256 * i;               // 0..1023
            int row = f >> 3;
            int c8 = f & 7;
            *(uint4*)&Bhs[row][c8 * 8] = *(const uint4*)(Bh + (size_t)(bn + row) * DM + kt + c8 * 8);
            *(uint4*)&Bls[row][c8 * 8] = *(const uint4*)(Bl + (size_t)(bn + row) * DM + kt + c8 * 8);
        }
        __syncthreads();
        #pragma unroll
        for (int ks = 0; ks < 2; ++ks) {
            half8 ah[4], al[4], bh[4], bl[4];
            #pragma unroll
            for (int mi = 0; mi < 4; ++mi) {
                ah[mi] = *(const half8*)&Ah[wm + mi * 16 + l15][ks * 32 + l4g * 8];
                al[mi] = *(const half8*)&Al[wm + mi * 16 + l15][ks * 32 + l4g * 8];
            }
            #pragma unroll
            for (int ni = 0; ni < 4; ++ni) {
                bh[ni] = *(const half8*)&Bhs[wn + ni * 16 + l15][ks * 32 + l4g * 8];
                bl[ni] = *(const half8*)&Bls[wn + ni * 16 + l15][ks * 32 + l4g * 8];
            }
            #pragma unroll
            for (int mi = 0; mi < 4; ++mi)
                #pragma unroll
                for (int ni = 0; ni < 4; ++ni) {
                    acc[mi][ni] = __builtin_amdgcn_mfma_f32_16x16x32_f16(ah[mi], bh[ni], acc[mi][ni], 0, 0, 0);
                    acc[mi][ni] = __builtin_amdgcn_mfma_f32_16x16x32_f16(ah[mi], bl[ni], acc[mi][ni], 0, 0, 0);
                    acc[mi][ni] = __builtin_amdgcn_mfma_f32_16x16x32_f16(al[mi], bh[ni], acc[mi][ni], 0, 0, 0);
                }
        }
        __syncthreads();
    }

    #pragma unroll
    for (int mi = 0; mi < 4; ++mi)
        #pragma unroll
        for (int ni = 0; ni < 4; ++ni) {
            int col = bn + wn + ni * 16 + l15;
            #pragma unroll
            for (int r = 0; r < 4; ++r) {
                int row = bm + wm + mi * 16 + l4g * 4 + r;
                float val = acc[mi][ni][r];
                _Float16 hv = (_Float16)val;
                Chi[(size_t)row * DM + col] = hv;
                Clo[(size_t)row * DM + col] = (_Float16)(val - (float)hv);
            }
        }
}

// ---------------------------------------------------------------------------
// V projection: A f32 -> fp16 staging, B fp16, C fp16 written TRANSPOSED as
// v^T [b][n=h*64+l][s].
// ---------------------------------------------------------------------------
__global__ __launch_bounds__(256) void gemm_v_k(
    const float* __restrict__ A, const _Float16* __restrict__ Bt,
    _Float16* __restrict__ C)
{
    __shared__ __align__(16) _Float16 As[128][72];
    __shared__ __align__(16) _Float16 Bs[128][72];

    const int t = threadIdx.x;
    const int lane = t & 63;
    const int w = t >> 6;
    const int wm = (w >> 1) * 64;
    const int wn = (w & 1) * 64;
    const int l15 = lane & 15;
    const int l4g = lane >> 4;

    const int bm = blockIdx.y * 128;
    const int bn = blockIdx.x * 128;

    f32x4 acc[4][4] = {};

    for (int kt = 0; kt < DM; kt += 64) {
        #pragma unroll
        for (int i = 0; i < 8; ++i) {
            int f = t + 256 * i;
            int row = f >> 4;
            int c4 = f & 15;
            float4 v = *(const float4*)(A + (size_t)(bm + row) * DM + kt + c4 * 4);
            half4 hv;
            hv[0] = (_Float16)v.x; hv[1] = (_Float16)v.y;
            hv[2] = (_Float16)v.z; hv[3] = (_Float16)v.w;
            *(half4*)&As[row][c4 * 4] = hv;
        }
        #pragma unroll
        for (int i = 0; i < 4; ++i) {
            int f = t + 256 * i;
            int row = f >> 3;
            int c8 = f & 7;
            *(uint4*)&Bs[row][c8 * 8] = *(const uint4*)(Bt + (size_t)(bn + row) * DM + kt + c8 * 8);
        }
        __syncthreads();
        #pragma unroll
        for (int ks = 0; ks < 2; ++ks) {
            half8 a[4], b[4];
            #pragma unroll
            for (int mi = 0; mi < 4; ++mi)
                a[mi] = *(const half8*)&As[wm + mi * 16 + l15][ks * 32 + l4g * 8];
            #pragma unroll
            for (int ni = 0; ni < 4; ++ni)
                b[ni] = *(const half8*)&Bs[wn + ni * 16 + l15][ks * 32 + l4g * 8];
            #pragma unroll
            for (int mi = 0; mi < 4; ++mi)
                #pragma unroll
                for (int ni = 0; ni < 4; ++ni)
                    acc[mi][ni] = __builtin_amdgcn_mfma_f32_16x16x32_f16(a[mi], b[ni], acc[mi][ni], 0, 0, 0);
        }
        __syncthreads();
    }

    #pragma unroll
    for (int mi = 0; mi < 4; ++mi)
        #pragma unroll
        for (int ni = 0; ni < 4; ++ni) {
            int col = bn + wn + ni * 16 + l15;
            #pragma unroll
            for (int r = 0; r < 4; ++r) {
                int row = bm + wm + mi * 16 + l4g * 4 + r;   // m = b*S + s
                C[((size_t)(row >> 10) * DM + col) * S_ + (row & 1023)] = (_Float16)acc[mi][ni][r];
            }
        }
}

// ---------------------------------------------------------------------------
// Output projection: A fp16 [8192][1024], B fp16 [n][k], C f32 + bias.
// ---------------------------------------------------------------------------
__global__ __launch_bounds__(256) void gemm_out_k(
    const _Float16* __restrict__ A, const _Float16* __restrict__ Bt,
    float* __restrict__ C, const float* __restrict__ bias)
{
    __shared__ __align__(16) _Float16 As[128][72];
    __shared__ __align__(16) _Float16 Bs[128][72];

    const int t = threadIdx.x;
    const int lane = t & 63;
    const int w = t >> 6;
    const int wm = (w >> 1) * 64;
    const int wn = (w & 1) * 64;
    const int l15 = lane & 15;
    const int l4g = lane >> 4;

    const int bm = blockIdx.y * 128;
    const int bn = blockIdx.x * 128;

    f32x4 acc[4][4] = {};

    for (int kt = 0; kt < DM; kt += 64) {
        #pragma unroll
        for (int i = 0; i < 4; ++i) {
            int f = t + 256 * i;
            int row = f >> 3;
            int c8 = f & 7;
            *(uint4*)&As[row][c8 * 8] = *(const uint4*)(A + (size_t)(bm + row) * DM + kt + c8 * 8);
            *(uint4*)&Bs[row][c8 * 8] = *(const uint4*)(Bt + (size_t)(bn + row) * DM + kt + c8 * 8);
        }
        __syncthreads();
        #pragma unroll
        for (int ks = 0; ks < 2; ++ks) {
            half8 a[4], b[4];
            #pragma unroll
            for (int mi = 0; mi < 4; ++mi)
                a[mi] = *(const half8*)&As[wm + mi * 16 + l15][ks * 32 + l4g * 8];
            #pragma unroll
            for (int ni = 0; ni < 4; ++ni)
                b[ni] = *(const half8*)&Bs[wn + ni * 16 + l15][ks * 32 + l4g * 8];
            #pragma unroll
            for (int mi = 0; mi < 4; ++mi)
                #pragma unroll
                for (int ni = 0; ni < 4; ++ni)
                    acc[mi][ni] = __builtin_amdgcn_mfma_f32_16x16x32_f16(a[mi], b[ni], acc[mi][ni], 0, 0, 0);
        }
        __syncthreads();
    }

    #pragma unroll
    for (int mi = 0; mi < 4; ++mi)
        #pragma unroll
        for (int ni = 0; ni < 4; ++ni) {
            int col = bn + wn + ni * 16 + l15;
            #pragma unroll
            for (int r = 0; r < 4; ++r) {
                int row = bm + wm + mi * 16 + l4g * 4 + r;
                C[(size_t)row * DM + col] = acc[mi][ni][r] + bias[col];
            }
        }
}

// ---------------------------------------------------------------------------
// Flash attention. 4 waves, 64 q-rows/block (16/wave), K/V tiles of 64.
// q,k: split fp16 hi/lo [b][s][h*64+l]. vT: [b][n][s] fp16. QK^T uses 3 MFMAs
// (hh+hl+lh) -> scores accurate to ~1e-4. Online softmax fp32.
// ---------------------------------------------------------------------------
__global__ __launch_bounds__(256) void attn_k(
    const _Float16* __restrict__ qhg, const _Float16* __restrict__ qlg,
    const _Float16* __restrict__ khg, const _Float16* __restrict__ klg,
    const _Float16* __restrict__ vtg, const unsigned char* __restrict__ mask,
    _Float16* __restrict__ ho)
{
    __shared__ __align__(16) _Float16 Kh[64][72];
    __shared__ __align__(16) _Float16 Kl[64][72];
    __shared__ __align__(16) _Float16 Vt[64][72];
    __shared__ __align__(16) unsigned char Ml[64 * 64];
    __shared__ __align__(16) _Float16 Pl[4][16][72];
    __shared__ int s_any[4];

    const int t = threadIdx.x;
    const int lane = t & 63;
    const int w = t >> 6;
    const int l15 = lane & 15;
    const int l4g = lane >> 4;

    const int qt = blockIdx.x;
    const int h = blockIdx.y;
    const int b = blockIdx.z;
    const size_t colbase = (size_t)h * DH;

    half8 qfh[2], qfl[2];
    {
        const int qrow = qt * 64 + w * 16 + l15;
        const size_t base = ((size_t)b * S_ + qrow) * DM + colbase;
        qfh[0] = *(const half8*)(qhg + base + l4g * 8);
        qfh[1] = *(const half8*)(qhg + base + 32 + l4g * 8);
        qfl[0] = *(const half8*)(qlg + base + l4g * 8);
        qfl[1] = *(const half8*)(qlg + base + 32 + l4g * 8);
    }

    float m[4], ls[4];
    f32x4 accO[4] = {};
    #pragma unroll
    for (int r = 0; r < 4; ++r) { m[r] = -__builtin_inff(); ls[r] = 0.0f; }

    for (int kt0 = 0; kt0 < S_; kt0 += 64) {
        #pragma unroll
        for (int i = 0; i < 2; ++i) {
            int f = t + 256 * i;               // 0..511
            int row = f >> 3;                  // 0..63
            int c8 = f & 7;
            const size_t kb = ((size_t)b * S_ + kt0 + row) * DM + colbase + c8 * 8;
            *(uint4*)&Kh[row][c8 * 8] = *(const uint4*)(khg + kb);
            *(uint4*)&Kl[row][c8 * 8] = *(const uint4*)(klg + kb);
            *(uint4*)&Vt[row][c8 * 8] =
                *(const uint4*)(vtg + ((size_t)b * DM + colbase + row) * S_ + kt0 + c8 * 8);
        }
        {
            uint4 mv = *(const uint4*)(mask + ((size_t)b * S_ + qt * 64 + (t >> 2)) * S_ + kt0 + (t & 3) * 16);
            *(uint4*)&Ml[t * 16] = mv;
            int a = (mv.x | mv.y | mv.z | mv.w) != 0;
            unsigned long long bal = __ballot(a);
            if (lane == 0) s_any[w] = (bal != 0ull);
        }
        __syncthreads();
        const int anyMask = s_any[0] | s_any[1] | s_any[2] | s_any[3];

        // ---- QK^T (split: hh + hl + lh) ----
        f32x4 sa[4] = {};
        #pragma unroll
        for (int ks = 0; ks < 2; ++ks) {
            #pragma unroll
            for (int ni = 0; ni < 4; ++ni) {
                half8 kfh = *(const half8*)&Kh[ni * 16 + l15][ks * 32 + l4g * 8];
                half8 kfl = *(const half8*)&Kl[ni * 16 + l15][ks * 32 + l4g * 8];
                sa[ni] = __builtin_amdgcn_mfma_f32_16x16x32_f16(qfh[ks], kfh, sa[ni], 0, 0, 0);
                sa[ni] = __builtin_amdgcn_mfma_f32_16x16x32_f16(qfh[ks], kfl, sa[ni], 0, 0, 0);
                sa[ni] = __builtin_amdgcn_mfma_f32_16x16x32_f16(qfl[ks], kfh, sa[ni], 0, 0, 0);
            }
        }
        #pragma unroll
        for (int ni = 0; ni < 4; ++ni)
            #pragma unroll
            for (int r = 0; r < 4; ++r)
                sa[ni][r] *= 0.125f;
        if (anyMask) {
            #pragma unroll
            for (int ni = 0; ni < 4; ++ni)
                #pragma unroll
                for (int r = 0; r < 4; ++r) {
                    int qr = w * 16 + l4g * 4 + r;
                    int kc = ni * 16 + l15;
                    if (Ml[qr * 64 + kc]) sa[ni][r] = -1e9f;
                }
        }
        // ---- online softmax (rows live in 16-lane groups) ----
        float rm[4];
        #pragma unroll
        for (int r = 0; r < 4; ++r)
            rm[r] = fmaxf(fmaxf(sa[0][r], sa[1][r]), fmaxf(sa[2][r], sa[3][r]));
        #pragma unroll
        for (int off = 1; off < 16; off <<= 1)
            #pragma unroll
            for (int r = 0; r < 4; ++r)
                rm[r] = fmaxf(rm[r], __shfl_xor(rm[r], off));
        float sf[4], mn[4];
        #pragma unroll
        for (int r = 0; r < 4; ++r) {
            mn[r] = fmaxf(m[r], rm[r]);
            sf[r] = __expf(m[r] - mn[r]);
            m[r] = mn[r];
        }
        float rs[4] = {0.f, 0.f, 0.f, 0.f};
        #pragma unroll
        for (int ni = 0; ni < 4; ++ni)
            #pragma unroll
            for (int r = 0; r < 4; ++r) {
                float p = __expf(sa[ni][r] - mn[r]);
                sa[ni][r] = p;
                rs[r] += p;
            }
        #pragma unroll
        for (int off = 1; off < 16; off <<= 1)
            #pragma unroll
            for (int r = 0; r < 4; ++r)
                rs[r] += __shfl_xor(rs[r], off);
        #pragma unroll
        for (int r = 0; r < 4; ++r)
            ls[r] = ls[r] * sf[r] + rs[r];
        #pragma unroll
        for (int ni = 0; ni < 4; ++ni)
            #pragma unroll
            for (int r = 0; r < 4; ++r)
                accO[ni][r] *= sf[r];
        #pragma unroll
        for (int ni = 0; ni < 4; ++ni)
            #pragma unroll
            for (int r = 0; r < 4; ++r)
                Pl[w][l4g * 4 + r][ni * 16 + l15] = (_Float16)sa[ni][r];
        __syncthreads();
        // ---- PV ----
        #pragma unroll
        for (int ks = 0; ks < 2; ++ks) {
            half8 pf = *(const half8*)&Pl[w][l15][ks * 32 + l4g * 8];
            #pragma unroll
            for (int ni = 0; ni < 4; ++ni) {
                half8 vf = *(const half8*)&Vt[ni * 16 + l15][ks * 32 + l4g * 8];
                accO[ni] = __builtin_amdgcn_mfma_f32_16x16x32_f16(pf, vf, accO[ni], 0, 0, 0);
            }
        }
        __syncthreads();
    }

    float inv[4];
    #pragma unroll
    for (int r = 0; r < 4; ++r) inv[r] = 1.0f / ls[r];
    #pragma unroll
    for (int ni = 0; ni < 4; ++ni)
        #pragma unroll
        for (int r = 0; r < 4; ++r) {
            int qr = qt * 64 + w * 16 + l4g * 4 + r;
            ho[((size_t)b * S_ + qr) * DM + colbase + ni * 16 + l15] =
                (_Float16)(accO[ni][r] * inv[r]);
        }
}

// ---------------------------------------------------------------------------
extern "C" void kernel_launch(void* const* d_in, const int* in_sizes, int n_in,
                              void* d_out, int out_size, void* d_ws, size_t ws_size,
                              hipStream_t stream)
{
    const float* Qs = (const float*)d_in[0];
    const float* Ks = (const float*)d_in[1];
    const float* Vs = (const float*)d_in[2];
    const unsigned char* mask = (const unsigned char*)d_in[3];
    const float* WQ = (const float*)d_in[4];
    const float* WK = (const float*)d_in[5];
    const float* WV = (const float*)d_in[6];
    const float* WO = (const float*)d_in[7];
    const float* bo = (const float*)d_in[8];

    char* ws = (char*)d_ws;
    const size_t MB = 1024 * 1024;
    _Float16* wqh = (_Float16*)(ws + 0 * MB);
    _Float16* wql = (_Float16*)(ws + 2 * MB);
    _Float16* wkh = (_Float16*)(ws + 4 * MB);
    _Float16* wkl = (_Float16*)(ws + 6 * MB);
    _Float16* wv  = (_Float16*)(ws + 8 * MB);
    _Float16* wo  = (_Float16*)(ws + 10 * MB);
    _Float16* qhi = (_Float16*)(ws + 12 * MB);   // 16 MB each
    _Float16* qlo = (_Float16*)(ws + 28 * MB);
    _Float16* khi = (_Float16*)(ws + 44 * MB);
    _Float16* klo = (_Float16*)(ws + 60 * MB);
    _Float16* vt  = (_Float16*)(ws + 76 * MB);
    _Float16* hh  = (_Float16*)(ws + 92 * MB);   // total 108 MB

    pack_k<<<4096, 256, 0, stream>>>(WQ, WK, WV, WO, wqh, wql, wkh, wkl, wv, wo);

    gemm_split_k<<<dim3(8, 64, 2), 256, 0, stream>>>(
        Qs, Ks, wqh, wql, wkh, wkl, qhi, qlo, khi, klo);

    gemm_v_k<<<dim3(8, 64, 1), 256, 0, stream>>>(Vs, wv, vt);

    attn_k<<<dim3(16, 16, 8), 256, 0, stream>>>(qhi, qlo, khi, klo, vt, mask, hh);

    gemm_out_k<<<dim3(8, 64, 1), 256, 0, stream>>>(hh, wo, (float*)d_out, bo);
}

// Round 4
// 336.921 us; speedup vs baseline: 1.1033x; 1.1033x over previous
//
#include <hip/hip_runtime.h>

#define DM 1024
#define H_ 16
#define DH 64
#define B_ 8
#define S_ 1024

typedef _Float16 half8 __attribute__((ext_vector_type(8)));
typedef _Float16 half4 __attribute__((ext_vector_type(4)));
typedef float f32x4 __attribute__((ext_vector_type(4)));
typedef float f32x16 __attribute__((ext_vector_type(16)));
typedef unsigned int uint;

// pack two f32 -> one u32 of 2 fp16 (compiler emits v_cvt + v_pack; m240: do NOT hand-asm)
static __device__ inline uint pkh(float a, float b) {
    _Float16 ha = (_Float16)a, hb = (_Float16)b;
    unsigned short ua = __builtin_bit_cast(unsigned short, ha);
    unsigned short ub = __builtin_bit_cast(unsigned short, hb);
    return (uint)ua | ((uint)ub << 16);
}
// v_permlane32_swap_b32 d, s: d.lanes[32:63] <-> s.lanes[0:31] (both modified)
#define PSWAP(d, s) asm volatile("v_permlane32_swap_b32 %0, %1" : "+v"(d), "+v"(s))

// ---------------------------------------------------------------------------
// Pack weights. W_Q/W_K -> fp16 hi/lo split pairs in B^T [n=h*64+l][k] layout.
// ---------------------------------------------------------------------------
__global__ __launch_bounds__(256) void pack_k(
    const float* __restrict__ WQ, const float* __restrict__ WK,
    const float* __restrict__ WV, const float* __restrict__ WO,
    _Float16* __restrict__ wqh, _Float16* __restrict__ wql,
    _Float16* __restrict__ wkh, _Float16* __restrict__ wkl,
    _Float16* __restrict__ wv,  _Float16* __restrict__ wo)
{
    int idx = blockIdx.x * 256 + threadIdx.x;
    int h  = idx >> 16;
    int kk = (idx >> 6) & 1023;
    int ll = idx & 63;
    int o = (h * 64 + ll) * DM + kk;
    float q = WQ[idx];
    _Float16 qh = (_Float16)q;
    wqh[o] = qh; wql[o] = (_Float16)(q - (float)qh);
    float k = WK[idx];
    _Float16 kh = (_Float16)k;
    wkh[o] = kh; wkl[o] = (_Float16)(k - (float)kh);
    wv[o] = (_Float16)WV[idx];
    wo[idx] = (_Float16)WO[idx];
}

// ---------------------------------------------------------------------------
// Mask pre-scan: scan[b][q64][k64] = any(mask in 64x64 tile). 2 KB output.
// ---------------------------------------------------------------------------
__global__ __launch_bounds__(256) void scan_k(
    const unsigned char* __restrict__ mask, unsigned char* __restrict__ scan)
{
    __shared__ int s_red[4];
    const int t = threadIdx.x;
    const int q64 = blockIdx.x, k64 = blockIdx.y, b = blockIdx.z;
    uint4 mv = *(const uint4*)(mask + ((size_t)b * S_ + q64 * 64 + (t >> 2)) * S_ + k64 * 64 + (t & 3) * 16);
    int a = (mv.x | mv.y | mv.z | mv.w) != 0;
    unsigned long long bal = __ballot(a);
    if ((t & 63) == 0) s_red[t >> 6] = (bal != 0ull);
    __syncthreads();
    if (t == 0)
        scan[(b * 16 + q64) * 16 + k64] =
            (unsigned char)(s_red[0] | s_red[1] | s_red[2] | s_red[3]);
}

// ---------------------------------------------------------------------------
// Split-precision GEMM (Q,K projections) — unchanged (validated r2).
// ---------------------------------------------------------------------------
__global__ __launch_bounds__(256) void gemm_split_k(
    const float* __restrict__ A0, const float* __restrict__ A1,
    const _Float16* __restrict__ Bh0, const _Float16* __restrict__ Bl0,
    const _Float16* __restrict__ Bh1, const _Float16* __restrict__ Bl1,
    _Float16* __restrict__ Chi0, _Float16* __restrict__ Clo0,
    _Float16* __restrict__ Chi1, _Float16* __restrict__ Clo1)
{
    const int z = blockIdx.z;
    const float* A = z ? A1 : A0;
    const _Float16* Bh = z ? Bh1 : Bh0;
    const _Float16* Bl = z ? Bl1 : Bl0;
    _Float16* Chi = z ? Chi1 : Chi0;
    _Float16* Clo = z ? Clo1 : Clo0;

    __shared__ __align__(16) _Float16 Ah[128][72];
    __shared__ __align__(16) _Float16 Al[128][72];
    __shared__ __align__(16) _Float16 Bhs[128][72];
    __shared__ __align__(16) _Float16 Bls[128][72];

    const int t = threadIdx.x;
    const int lane = t & 63;
    const int w = t >> 6;
    const int wm = (w >> 1) * 64;
    const int wn = (w & 1) * 64;
    const int l15 = lane & 15;
    const int l4g = lane >> 4;

    const int bm = blockIdx.y * 128;
    const int bn = blockIdx.x * 128;

    f32x4 acc[4][4] = {};

    for (int kt = 0; kt < DM; kt += 64) {
        #pragma unroll
        for (int i = 0; i < 8; ++i) {
            int f = t + 256 * i;
            int row = f >> 4;
            int c4 = f & 15;
            float4 v = *(const float4*)(A + (size_t)(bm + row) * DM + kt + c4 * 4);
            half4 hv, lv;
            hv[0] = (_Float16)v.x; lv[0] = (_Float16)(v.x - (float)hv[0]);
            hv[1] = (_Float16)v.y; lv[1] = (_Float16)(v.y - (float)hv[1]);
            hv[2] = (_Float16)v.z; lv[2] = (_Float16)(v.z - (float)hv[2]);
            hv[3] = (_Float16)v.w; lv[3] = (_Float16)(v.w - (float)hv[3]);
            *(half4*)&Ah[row][c4 * 4] = hv;
            *(half4*)&Al[row][c4 * 4] = lv;
        }
        #pragma unroll
        for (int i = 0; i < 4; ++i) {
            int f = t + 256 * i;
            int row = f >> 3;
            int c8 = f & 7;
            *(uint4*)&Bhs[row][c8 * 8] = *(const uint4*)(Bh + (size_t)(bn + row) * DM + kt + c8 * 8);
            *(uint4*)&Bls[row][c8 * 8] = *(const uint4*)(Bl + (size_t)(bn + row) * DM + kt + c8 * 8);
        }
        __syncthreads();
        #pragma unroll
        for (int ks = 0; ks < 2; ++ks) {
            half8 ah[4], al[4], bh[4], bl[4];
            #pragma unroll
            for (int mi = 0; mi < 4; ++mi) {
                ah[mi] = *(const half8*)&Ah[wm + mi * 16 + l15][ks * 32 + l4g * 8];
                al[mi] = *(const half8*)&Al[wm + mi * 16 + l15][ks * 32 + l4g * 8];
            }
            #pragma unroll
            for (int ni = 0; ni < 4; ++ni) {
                bh[ni] = *(const half8*)&Bhs[wn + ni * 16 + l15][ks * 32 + l4g * 8];
                bl[ni] = *(const half8*)&Bls[wn + ni * 16 + l15][ks * 32 + l4g * 8];
            }
            #pragma unroll
            for (int mi = 0; mi < 4; ++mi)
                #pragma unroll
                for (int ni = 0; ni < 4; ++ni) {
                    acc[mi][ni] = __builtin_amdgcn_mfma_f32_16x16x32_f16(ah[mi], bh[ni], acc[mi][ni], 0, 0, 0);
                    acc[mi][ni] = __builtin_amdgcn_mfma_f32_16x16x32_f16(ah[mi], bl[ni], acc[mi][ni], 0, 0, 0);
                    acc[mi][ni] = __builtin_amdgcn_mfma_f32_16x16x32_f16(al[mi], bh[ni], acc[mi][ni], 0, 0, 0);
                }
        }
        __syncthreads();
    }

    #pragma unroll
    for (int mi = 0; mi < 4; ++mi)
        #pragma unroll
        for (int ni = 0; ni < 4; ++ni) {
            int col = bn + wn + ni * 16 + l15;
            #pragma unroll
            for (int r = 0; r < 4; ++r) {
                int row = bm + wm + mi * 16 + l4g * 4 + r;
                float val = acc[mi][ni][r];
                _Float16 hv = (_Float16)val;
                Chi[(size_t)row * DM + col] = hv;
                Clo[(size_t)row * DM + col] = (_Float16)(val - (float)hv);
            }
        }
}

// ---------------------------------------------------------------------------
// V projection -> v^T [b][n][s]  — unchanged (validated r2).
// ---------------------------------------------------------------------------
__global__ __launch_bounds__(256) void gemm_v_k(
    const float* __restrict__ A, const _Float16* __restrict__ Bt,
    _Float16* __restrict__ C)
{
    __shared__ __align__(16) _Float16 As[128][72];
    __shared__ __align__(16) _Float16 Bs[128][72];

    const int t = threadIdx.x;
    const int lane = t & 63;
    const int w = t >> 6;
    const int wm = (w >> 1) * 64;
    const int wn = (w & 1) * 64;
    const int l15 = lane & 15;
    const int l4g = lane >> 4;

    const int bm = blockIdx.y * 128;
    const int bn = blockIdx.x * 128;

    f32x4 acc[4][4] = {};

    for (int kt = 0; kt < DM; kt += 64) {
        #pragma unroll
        for (int i = 0; i < 8; ++i) {
            int f = t + 256 * i;
            int row = f >> 4;
            int c4 = f & 15;
            float4 v = *(const float4*)(A + (size_t)(bm + row) * DM + kt + c4 * 4);
            half4 hv;
            hv[0] = (_Float16)v.x; hv[1] = (_Float16)v.y;
            hv[2] = (_Float16)v.z; hv[3] = (_Float16)v.w;
            *(half4*)&As[row][c4 * 4] = hv;
        }
        #pragma unroll
        for (int i = 0; i < 4; ++i) {
            int f = t + 256 * i;
            int row = f >> 3;
            int c8 = f & 7;
            *(uint4*)&Bs[row][c8 * 8] = *(const uint4*)(Bt + (size_t)(bn + row) * DM + kt + c8 * 8);
        }
        __syncthreads();
        #pragma unroll
        for (int ks = 0; ks < 2; ++ks) {
            half8 a[4], b[4];
            #pragma unroll
            for (int mi = 0; mi < 4; ++mi)
                a[mi] = *(const half8*)&As[wm + mi * 16 + l15][ks * 32 + l4g * 8];
            #pragma unroll
            for (int ni = 0; ni < 4; ++ni)
                b[ni] = *(const half8*)&Bs[wn + ni * 16 + l15][ks * 32 + l4g * 8];
            #pragma unroll
            for (int mi = 0; mi < 4; ++mi)
                #pragma unroll
                for (int ni = 0; ni < 4; ++ni)
                    acc[mi][ni] = __builtin_amdgcn_mfma_f32_16x16x32_f16(a[mi], b[ni], acc[mi][ni], 0, 0, 0);
        }
        __syncthreads();
    }

    #pragma unroll
    for (int mi = 0; mi < 4; ++mi)
        #pragma unroll
        for (int ni = 0; ni < 4; ++ni) {
            int col = bn + wn + ni * 16 + l15;
            #pragma unroll
            for (int r = 0; r < 4; ++r) {
                int row = bm + wm + mi * 16 + l4g * 4 + r;
                C[((size_t)(row >> 10) * DM + col) * S_ + (row & 1023)] = (_Float16)acc[mi][ni][r];
            }
        }
}

// ---------------------------------------------------------------------------
// Output projection — unchanged (validated r2).
// ---------------------------------------------------------------------------
__global__ __launch_bounds__(256) void gemm_out_k(
    const _Float16* __restrict__ A, const _Float16* __restrict__ Bt,
    float* __restrict__ C, const float* __restrict__ bias)
{
    __shared__ __align__(16) _Float16 As[128][72];
    __shared__ __align__(16) _Float16 Bs[128][72];

    const int t = threadIdx.x;
    const int lane = t & 63;
    const int w = t >> 6;
    const int wm = (w >> 1) * 64;
    const int wn = (w & 1) * 64;
    const int l15 = lane & 15;
    const int l4g = lane >> 4;

    const int bm = blockIdx.y * 128;
    const int bn = blockIdx.x * 128;

    f32x4 acc[4][4] = {};

    for (int kt = 0; kt < DM; kt += 64) {
        #pragma unroll
        for (int i = 0; i < 4; ++i) {
            int f = t + 256 * i;
            int row = f >> 3;
            int c8 = f & 7;
            *(uint4*)&As[row][c8 * 8] = *(const uint4*)(A + (size_t)(bm + row) * DM + kt + c8 * 8);
            *(uint4*)&Bs[row][c8 * 8] = *(const uint4*)(Bt + (size_t)(bn + row) * DM + kt + c8 * 8);
        }
        __syncthreads();
        #pragma unroll
        for (int ks = 0; ks < 2; ++ks) {
            half8 a[4], b[4];
            #pragma unroll
            for (int mi = 0; mi < 4; ++mi)
                a[mi] = *(const half8*)&As[wm + mi * 16 + l15][ks * 32 + l4g * 8];
            #pragma unroll
            for (int ni = 0; ni < 4; ++ni)
                b[ni] = *(const half8*)&Bs[wn + ni * 16 + l15][ks * 32 + l4g * 8];
            #pragma unroll
            for (int mi = 0; mi < 4; ++mi)
                #pragma unroll
                for (int ni = 0; ni < 4; ++ni)
                    acc[mi][ni] = __builtin_amdgcn_mfma_f32_16x16x32_f16(a[mi], b[ni], acc[mi][ni], 0, 0, 0);
        }
        __syncthreads();
    }

    #pragma unroll
    for (int mi = 0; mi < 4; ++mi)
        #pragma unroll
        for (int ni = 0; ni < 4; ++ni) {
            int col = bn + wn + ni * 16 + l15;
            #pragma unroll
            for (int r = 0; r < 4; ++r) {
                int row = bm + wm + mi * 16 + l4g * 4 + r;
                C[(size_t)row * DM + col] = acc[mi][ni][r] + bias[col];
            }
        }
}

// ---------------------------------------------------------------------------
// Flash attention, 32x32 swapped-operand structure (m214-style).
// QK^T = mfma(K, Q): lane owns q = lane&31 scores lane-locally (C/D layout
// col=lane&31, row=(e&3)+8*(e>>2)+4*(lane>>5) — HW-verified m74/m101).
// PV = mfma(V^T, P): accO q lane-local. P -> A-frags via pack+permlane32_swap:
// PSWAP(x, y) moves y.lower -> x.upper and x.upper -> y.lower, which is the
// direction needed (x keeps its lower-lane k-pair, gains y's lower-lane pair
// on upper lanes). Round-3 bug: arguments were inverted.
// ---------------------------------------------------------------------------
__global__ __launch_bounds__(256) void attn_k(
    const _Float16* __restrict__ qhg, const _Float16* __restrict__ qlg,
    const _Float16* __restrict__ khg, const _Float16* __restrict__ klg,
    const _Float16* __restrict__ vtg, const unsigned char* __restrict__ maskg,
    const unsigned char* __restrict__ scanp, _Float16* __restrict__ ho)
{
    __shared__ __align__(16) _Float16 Kh[64][72];
    __shared__ __align__(16) _Float16 Kl[64][72];
    __shared__ __align__(16) _Float16 Vt[64][72];

    const int t = threadIdx.x;
    const int lane = t & 63;
    const int w = t >> 6;
    const int l31 = lane & 31;
    const int hi = lane >> 5;

    // XCD swizzle: 16 heads per XCD.
    const int j = blockIdx.y + 16 * blockIdx.z;          // 0..127
    const int head = 16 * blockIdx.x + (j >> 3);         // 0..127
    const int qt = j & 7;
    const int h = head & 15;
    const int b = head >> 4;

    const int colbase = h * DH;
    const int qrow = qt * 128 + w * 32 + l31;

    // Q fragments (B-operand): lane holds Q[d = ds*16 + hi*8 + e][q = l31]
    half8 qfh[4], qfl[4];
    {
        const size_t base = ((size_t)b * S_ + qrow) * DM + colbase;
        #pragma unroll
        for (int ds = 0; ds < 4; ++ds) {
            qfh[ds] = *(const half8*)(qhg + base + ds * 16 + hi * 8);
            qfl[ds] = *(const half8*)(qlg + base + ds * 16 + hi * 8);
        }
    }

    float m_q = -1e30f, ls = 0.0f;
    f32x16 accO0 = {};   // d 0..31 rows, q = lane&31 col
    f32x16 accO1 = {};   // d 32..63

    const int r0 = t >> 3;            // 0..31
    const int c0 = (t & 7) * 8;
    const _Float16* kph = khg + ((size_t)b * S_) * DM + colbase;
    const _Float16* kpl = klg + ((size_t)b * S_) * DM + colbase;
    const _Float16* vp  = vtg + ((size_t)b * DM + colbase) * S_;
    const unsigned char* sc0 = scanp + (b * 16 + 2 * qt) * 16;
    const unsigned char* sc1 = scanp + (b * 16 + 2 * qt + 1) * 16;

    uint4 akh0, akh1, akl0, akl1, av0, av1;
#define ALOAD(KT) do { \
        akh0 = *(const uint4*)(kph + (size_t)((KT) * 64 + r0) * DM + c0);       \
        akh1 = *(const uint4*)(kph + (size_t)((KT) * 64 + 32 + r0) * DM + c0);  \
        akl0 = *(const uint4*)(kpl + (size_t)((KT) * 64 + r0) * DM + c0);       \
        akl1 = *(const uint4*)(kpl + (size_t)((KT) * 64 + 32 + r0) * DM + c0);  \
        av0  = *(const uint4*)(vp + (size_t)r0 * S_ + (KT) * 64 + c0);          \
        av1  = *(const uint4*)(vp + (size_t)(32 + r0) * S_ + (KT) * 64 + c0);   \
    } while (0)
#define AWRITE() do { \
        *(uint4*)&Kh[r0][c0] = akh0; *(uint4*)&Kh[32 + r0][c0] = akh1; \
        *(uint4*)&Kl[r0][c0] = akl0; *(uint4*)&Kl[32 + r0][c0] = akl1; \
        *(uint4*)&Vt[r0][c0] = av0;  *(uint4*)&Vt[32 + r0][c0] = av1;  \
    } while (0)

    ALOAD(0);
    AWRITE();
    int msk = sc0[0] | sc1[0];

    const float SC = 0.125f * 1.44269504089f;   // scale * log2(e)

    for (int kt = 0; kt < 16; ++kt) {
        __syncthreads();                         // LDS[kt] visible
        const int mskcur = msk;
        if (kt < 15) {
            ALOAD(kt + 1);                       // in flight under compute
            msk = sc0[kt + 1] | sc1[kt + 1];
        }

        // ---- QK^T swapped: sa[kpos][q] ----
        f32x16 sa0 = {}, sa1 = {};
        #pragma unroll
        for (int ds = 0; ds < 4; ++ds) {
            half8 kh0 = *(const half8*)&Kh[l31][ds * 16 + hi * 8];
            half8 kl0 = *(const half8*)&Kl[l31][ds * 16 + hi * 8];
            half8 kh1 = *(const half8*)&Kh[32 + l31][ds * 16 + hi * 8];
            half8 kl1 = *(const half8*)&Kl[32 + l31][ds * 16 + hi * 8];
            sa0 = __builtin_amdgcn_mfma_f32_32x32x16_f16(kh0, qfh[ds], sa0, 0, 0, 0);
            sa0 = __builtin_amdgcn_mfma_f32_32x32x16_f16(kh0, qfl[ds], sa0, 0, 0, 0);
            sa0 = __builtin_amdgcn_mfma_f32_32x32x16_f16(kl0, qfh[ds], sa0, 0, 0, 0);
            sa1 = __builtin_amdgcn_mfma_f32_32x32x16_f16(kh1, qfh[ds], sa1, 0, 0, 0);
            sa1 = __builtin_amdgcn_mfma_f32_32x32x16_f16(kh1, qfl[ds], sa1, 0, 0, 0);
            sa1 = __builtin_amdgcn_mfma_f32_32x32x16_f16(kl1, qfh[ds], sa1, 0, 0, 0);
        }
        #pragma unroll
        for (int e = 0; e < 16; ++e) { sa0[e] *= SC; sa1[e] *= SC; }

        if (mskcur) {   // rare path: per-lane mask bytes from global
            const unsigned char* mrow = maskg + ((size_t)b * S_ + qrow) * S_ + kt * 64;
            #pragma unroll
            for (int e = 0; e < 16; ++e) {
                int kl_ = (e & 3) + 8 * (e >> 2) + 4 * hi;
                if (mrow[kl_]) sa0[e] = -1e9f;
                if (mrow[32 + kl_]) sa1[e] = -1e9f;
            }
        }

        // ---- online softmax, q lane-local ----
        float rm = sa0[0];
        #pragma unroll
        for (int e = 1; e < 16; ++e) rm = fmaxf(rm, sa0[e]);
        #pragma unroll
        for (int e = 0; e < 16; ++e) rm = fmaxf(rm, sa1[e]);
        rm = fmaxf(rm, __shfl_xor(rm, 32));
        const float mn = fmaxf(m_q, rm);
        const float sfac = exp2f(m_q - mn);
        m_q = mn;
        float rs = 0.0f;
        #pragma unroll
        for (int e = 0; e < 16; ++e) { sa0[e] = exp2f(sa0[e] - mn); rs += sa0[e]; }
        #pragma unroll
        for (int e = 0; e < 16; ++e) { sa1[e] = exp2f(sa1[e] - mn); rs += sa1[e]; }
        rs += __shfl_xor(rs, 32);
        ls = ls * sfac + rs;
        #pragma unroll
        for (int e = 0; e < 16; ++e) { accO0[e] *= sfac; accO1[e] *= sfac; }

        // ---- P -> A-frags (T12), then PV ----
        // lane holds k_local = (e&3) + 8*(e>>2) + 4*hi; pf[kc] needs element e
        // = P[k = kc*16 + hi*8 + e]. PSWAP(x, y): x.upper <- y.lower (and
        // y.lower <- x.upper) — so x keeps lower-lane pairs, gains y's.
        half8 pf[4];
        {
            uint c0_ = pkh(sa0[0], sa0[1]),  c1_ = pkh(sa0[2], sa0[3]);
            uint c2_ = pkh(sa0[4], sa0[5]),  c3_ = pkh(sa0[6], sa0[7]);
            uint c4_ = pkh(sa0[8], sa0[9]),  c5_ = pkh(sa0[10], sa0[11]);
            uint c6_ = pkh(sa0[12], sa0[13]), c7_ = pkh(sa0[14], sa0[15]);
            PSWAP(c0_, c2_); PSWAP(c1_, c3_);
            PSWAP(c4_, c6_); PSWAP(c5_, c7_);
            uint4 u0 = {c0_, c1_, c2_, c3_}, u1 = {c4_, c5_, c6_, c7_};
            pf[0] = __builtin_bit_cast(half8, u0);
            pf[1] = __builtin_bit_cast(half8, u1);
        }
        {
            uint c0_ = pkh(sa1[0], sa1[1]),  c1_ = pkh(sa1[2], sa1[3]);
            uint c2_ = pkh(sa1[4], sa1[5]),  c3_ = pkh(sa1[6], sa1[7]);
            uint c4_ = pkh(sa1[8], sa1[9]),  c5_ = pkh(sa1[10], sa1[11]);
            uint c6_ = pkh(sa1[12], sa1[13]), c7_ = pkh(sa1[14], sa1[15]);
            PSWAP(c0_, c2_); PSWAP(c1_, c3_);
            PSWAP(c4_, c6_); PSWAP(c5_, c7_);
            uint4 u0 = {c0_, c1_, c2_, c3_}, u1 = {c4_, c5_, c6_, c7_};
            pf[2] = __builtin_bit_cast(half8, u0);
            pf[3] = __builtin_bit_cast(half8, u1);
        }
        // PV: O^T[d][q] += V^T[d][k] * P[k][q]
        #pragma unroll
        for (int kc = 0; kc < 4; ++kc) {
            half8 vf0 = *(const half8*)&Vt[l31][kc * 16 + hi * 8];
            half8 vf1 = *(const half8*)&Vt[32 + l31][kc * 16 + hi * 8];
            accO0 = __builtin_amdgcn_mfma_f32_32x32x16_f16(vf0, pf[kc], accO0, 0, 0, 0);
            accO1 = __builtin_amdgcn_mfma_f32_32x32x16_f16(vf1, pf[kc], accO1, 0, 0, 0);
        }

        __syncthreads();                         // all waves done reading LDS[kt]
        if (kt < 15) AWRITE();                   // stage LDS[kt+1]
    }
#undef ALOAD
#undef AWRITE

    // ---- epilogue: O[q][d] = accO^T / ls ----
    const float inv = 1.0f / ls;
    _Float16* orow = ho + ((size_t)b * S_ + qrow) * DM + colbase;
    #pragma unroll
    for (int g2 = 0; g2 < 4; ++g2) {
        half4 hv0, hv1;
        #pragma unroll
        for (int e = 0; e < 4; ++e) {
            hv0[e] = (_Float16)(accO0[g2 * 4 + e] * inv);
            hv1[e] = (_Float16)(accO1[g2 * 4 + e] * inv);
        }
        *(half4*)(orow + g2 * 8 + hi * 4) = hv0;        // d = 8*g2 + 4*hi + e
        *(half4*)(orow + 32 + g2 * 8 + hi * 4) = hv1;   // d = 32 + ...
    }
}

// ---------------------------------------------------------------------------
extern "C" void kernel_launch(void* const* d_in, const int* in_sizes, int n_in,
                              void* d_out, int out_size, void* d_ws, size_t ws_size,
                              hipStream_t stream)
{
    const float* Qs = (const float*)d_in[0];
    const float* Ks = (const float*)d_in[1];
    const float* Vs = (const float*)d_in[2];
    const unsigned char* mask = (const unsigned char*)d_in[3];
    const float* WQ = (const float*)d_in[4];
    const float* WK = (const float*)d_in[5];
    const float* WV = (const float*)d_in[6];
    const float* WO = (const float*)d_in[7];
    const float* bo = (const float*)d_in[8];

    char* ws = (char*)d_ws;
    const size_t MB = 1024 * 1024;
    _Float16* wqh = (_Float16*)(ws + 0 * MB);
    _Float16* wql = (_Float16*)(ws + 2 * MB);
    _Float16* wkh = (_Float16*)(ws + 4 * MB);
    _Float16* wkl = (_Float16*)(ws + 6 * MB);
    _Float16* wv  = (_Float16*)(ws + 8 * MB);
    _Float16* wo  = (_Float16*)(ws + 10 * MB);
    _Float16* qhi = (_Float16*)(ws + 12 * MB);
    _Float16* qlo = (_Float16*)(ws + 28 * MB);
    _Float16* khi = (_Float16*)(ws + 44 * MB);
    _Float16* klo = (_Float16*)(ws + 60 * MB);
    _Float16* vt  = (_Float16*)(ws + 76 * MB);
    _Float16* hh  = (_Float16*)(ws + 92 * MB);
    unsigned char* scan = (unsigned char*)(ws + 108 * MB);   // 2 KB

    pack_k<<<4096, 256, 0, stream>>>(WQ, WK, WV, WO, wqh, wql, wkh, wkl, wv, wo);
    scan_k<<<dim3(16, 16, 8), 256, 0, stream>>>(mask, scan);

    gemm_split_k<<<dim3(8, 64, 2), 256, 0, stream>>>(
        Qs, Ks, wqh, wql, wkh, wkl, qhi, qlo, khi, klo);

    gemm_v_k<<<dim3(8, 64, 1), 256, 0, stream>>>(Vs, wv, vt);

    attn_k<<<dim3(8, 16, 8), 256, 0, stream>>>(qhi, qlo, khi, klo, vt, mask, scan, hh);

    gemm_out_k<<<dim3(8, 64, 1), 256, 0, stream>>>(hh, wo, (float*)d_out, bo);
}

// Round 5
// 310.093 us; speedup vs baseline: 1.1988x; 1.0865x over previous
//
#include <hip/hip_runtime.h>

#define DM 1024
#define H_ 16
#define DH 64
#define B_ 8
#define S_ 1024

typedef _Float16 half8 __attribute__((ext_vector_type(8)));
typedef _Float16 half4 __attribute__((ext_vector_type(4)));
typedef float f32x4 __attribute__((ext_vector_type(4)));
typedef float f32x16 __attribute__((ext_vector_type(16)));
typedef unsigned int uint;

// pack two f32 -> one u32 of 2 fp16
static __device__ inline uint pkh(float a, float b) {
    _Float16 ha = (_Float16)a, hb = (_Float16)b;
    unsigned short ua = __builtin_bit_cast(unsigned short, ha);
    unsigned short ub = __builtin_bit_cast(unsigned short, hb);
    return (uint)ua | ((uint)ub << 16);
}
// v_permlane32_swap_b32 d, s: d.lanes[32:63] <-> s.lanes[0:31]
#define PSWAP(d, s) asm volatile("v_permlane32_swap_b32 %0, %1" : "+v"(d), "+v"(s))

// async global->LDS, 16 B per lane; LDS dest base must be wave-uniform
static __device__ __forceinline__ void gload16(const _Float16* g, _Float16* l) {
    __builtin_amdgcn_global_load_lds(
        (const __attribute__((address_space(1))) unsigned int*)(const void*)g,
        (__attribute__((address_space(3))) unsigned int*)(void*)l,
        16, 0, 0);
}

// ---------------------------------------------------------------------------
// Pack projection weights with LDS transpose.
// Input W[h][k][l]; output rows n=h*64+l, cols k, fp16 (hi/lo for WQ,WK),
// with 16B-chunk XOR swizzle: logical chunk c stored at phys (c&~7)|((c&7)^(n&7)).
// ---------------------------------------------------------------------------
__global__ __launch_bounds__(256) void packw_k(
    const float* __restrict__ WQ, const float* __restrict__ WK,
    const float* __restrict__ WV,
    _Float16* __restrict__ wqh, _Float16* __restrict__ wql,
    _Float16* __restrict__ wkh, _Float16* __restrict__ wkl,
    _Float16* __restrict__ wv)
{
    __shared__ __align__(16) _Float16 Lh[64][72];
    __shared__ __align__(16) _Float16 Ll[64][72];
    const int t = threadIdx.x;
    const int kb = blockIdx.x;   // k-block of 64 (16)
    const int h  = blockIdx.y;   // head (16)

    #pragma unroll
    for (int s = 0; s < 3; ++s) {
        const float* W = (s == 0) ? WQ : ((s == 1) ? WK : WV);
        const int krow = t >> 2, lc = t & 3;
        const float* rp = W + (((size_t)h * 1024 + kb * 64 + krow) * 64 + lc * 16);
        #pragma unroll
        for (int q4 = 0; q4 < 4; ++q4) {
            float4 f = ((const float4*)rp)[q4];
            float vv0 = f.x, vv1 = f.y, vv2 = f.z, vv3 = f.w;
            int l0 = lc * 16 + q4 * 4;
            _Float16 h0 = (_Float16)vv0; Lh[l0 + 0][krow] = h0; Ll[l0 + 0][krow] = (_Float16)(vv0 - (float)h0);
            _Float16 h1 = (_Float16)vv1; Lh[l0 + 1][krow] = h1; Ll[l0 + 1][krow] = (_Float16)(vv1 - (float)h1);
            _Float16 h2 = (_Float16)vv2; Lh[l0 + 2][krow] = h2; Ll[l0 + 2][krow] = (_Float16)(vv2 - (float)h2);
            _Float16 h3 = (_Float16)vv3; Lh[l0 + 3][krow] = h3; Ll[l0 + 3][krow] = (_Float16)(vv3 - (float)h3);
        }
        __syncthreads();
        const int l = t >> 2, pc = t & 3;
        #pragma unroll
        for (int hp = 0; hp < 2; ++hp) {
            int p = pc + 4 * hp;               // phys chunk within this 64-k block
            int lc2 = p ^ (l & 7);             // logical chunk stored here
            half8 vh = *(const half8*)&Lh[l][lc2 * 8];
            half8 vl = *(const half8*)&Ll[l][lc2 * 8];
            size_t off = (size_t)(h * 64 + l) * DM + kb * 64 + p * 8;
            if (s == 0) { *(half8*)(wqh + off) = vh; *(half8*)(wql + off) = vl; }
            else if (s == 1) { *(half8*)(wkh + off) = vh; *(half8*)(wkl + off) = vl; }
            else { *(half8*)(wv + off) = vh; }
        }
        __syncthreads();
    }
}

// ---------------------------------------------------------------------------
// Pack W_out: already [n][k]; fp16 convert + chunk XOR (no transpose).
// ---------------------------------------------------------------------------
__global__ __launch_bounds__(256) void packo_k(
    const float* __restrict__ WO, _Float16* __restrict__ wo)
{
    int idx8 = blockIdx.x * 256 + threadIdx.x;   // 0..131071
    int n = idx8 >> 7;
    int c = idx8 & 127;
    int p = (c & ~7) | ((c & 7) ^ (n & 7));
    const float* rp = WO + ((size_t)n * DM + c * 8);
    float4 a = ((const float4*)rp)[0];
    float4 b = ((const float4*)rp)[1];
    half8 v;
    v[0] = (_Float16)a.x; v[1] = (_Float16)a.y; v[2] = (_Float16)a.z; v[3] = (_Float16)a.w;
    v[4] = (_Float16)b.x; v[5] = (_Float16)b.y; v[6] = (_Float16)b.z; v[7] = (_Float16)b.w;
    *(half8*)(wo + (size_t)n * DM + p * 8) = v;
}

// ---------------------------------------------------------------------------
// Mask pre-scan (unchanged, validated).
// ---------------------------------------------------------------------------
__global__ __launch_bounds__(256) void scan_k(
    const unsigned char* __restrict__ mask, unsigned char* __restrict__ scan)
{
    __shared__ int s_red[4];
    const int t = threadIdx.x;
    const int q64 = blockIdx.x, k64 = blockIdx.y, b = blockIdx.z;
    uint4 mv = *(const uint4*)(mask + ((size_t)b * S_ + q64 * 64 + (t >> 2)) * S_ + k64 * 64 + (t & 3) * 16);
    int a = (mv.x | mv.y | mv.z | mv.w) != 0;
    unsigned long long bal = __ballot(a);
    if ((t & 63) == 0) s_red[t >> 6] = (bal != 0ull);
    __syncthreads();
    if (t == 0)
        scan[(b * 16 + q64) * 16 + k64] =
            (unsigned char)(s_red[0] | s_red[1] | s_red[2] | s_red[3]);
}

// ---------------------------------------------------------------------------
// Split-precision GEMM (Q,K proj): C = A(f32)*Bt^T, 3 MFMAs (hh+hl+lh).
// B via global_load_lds from pre-XOR-packed layout (linear LDS, swizzled read).
// A reg-staged with T14 prefetch, cvt to hi/lo in padded LDS.
// XCD-group block remap: 8 blocks sharing an A-panel land on one XCD's L2.
// ---------------------------------------------------------------------------
__global__ __launch_bounds__(256) void gemm_split_k(
    const float* __restrict__ A0, const float* __restrict__ A1,
    const _Float16* __restrict__ Bh0, const _Float16* __restrict__ Bl0,
    const _Float16* __restrict__ Bh1, const _Float16* __restrict__ Bl1,
    _Float16* __restrict__ Chi0, _Float16* __restrict__ Clo0,
    _Float16* __restrict__ Chi1, _Float16* __restrict__ Clo1)
{
    const int lid = blockIdx.x + 8 * blockIdx.y + 512 * blockIdx.z;
    const int xcd = lid & 7, k2 = lid >> 3;
    const int G = xcd * 16 + (k2 >> 3);
    const int bxv = k2 & 7, byv = G & 63, z = G >> 6;

    const float* A = z ? A1 : A0;
    const _Float16* Bh = z ? Bh1 : Bh0;
    const _Float16* Bl = z ? Bl1 : Bl0;
    _Float16* Chi = z ? Chi1 : Chi0;
    _Float16* Clo = z ? Clo1 : Clo0;

    __shared__ __align__(16) _Float16 SM[34816];
    _Float16* Ah  = SM;             // [128][72] padded
    _Float16* Al  = SM + 9216;      // [128][72]
    _Float16* Bhs = SM + 18432;     // [128][64] linear (gload dest)
    _Float16* Bls = SM + 26624;     // [128][64]

    const int t = threadIdx.x;
    const int lane = t & 63;
    const int w = t >> 6;
    const int wm = (w >> 1) * 64;
    const int wn = (w & 1) * 64;
    const int l15 = lane & 15;
    const int l4g = lane >> 4;

    const int bm = byv * 128;
    const int bn = bxv * 128;

    f32x4 acc[4][4] = {};

    const int arow = t >> 4, ac4 = t & 15;
    float4 ar[8];
    auto aload = [&](int KT) {
        #pragma unroll
        for (int i = 0; i < 8; ++i)
            ar[i] = *(const float4*)(A + (size_t)(bm + arow + 16 * i) * DM + KT * 64 + ac4 * 4);
    };
    auto awr = [&]() {
        #pragma unroll
        for (int i = 0; i < 8; ++i) {
            float4 v = ar[i];
            half4 hv, lv;
            hv[0] = (_Float16)v.x; lv[0] = (_Float16)(v.x - (float)hv[0]);
            hv[1] = (_Float16)v.y; lv[1] = (_Float16)(v.y - (float)hv[1]);
            hv[2] = (_Float16)v.z; lv[2] = (_Float16)(v.z - (float)hv[2]);
            hv[3] = (_Float16)v.w; lv[3] = (_Float16)(v.w - (float)hv[3]);
            *(half4*)&Ah[(arow + 16 * i) * 72 + ac4 * 4] = hv;
            *(half4*)&Al[(arow + 16 * i) * 72 + ac4 * 4] = lv;
        }
    };
    auto bgl = [&](int KT) {
        #pragma unroll
        for (int j = 0; j < 4; ++j) {
            int rr = w * 32 + j * 8 + (lane >> 3);
            const size_t so = (size_t)(bn + rr) * DM + KT * 64 + (lane & 7) * 8;
            gload16(Bh + so, &Bhs[(w * 32 + j * 8) * 64]);
            gload16(Bl + so, &Bls[(w * 32 + j * 8) * 64]);
        }
    };

    aload(0);
    bgl(0);
    for (int kt = 0; kt < 16; ++kt) {
        awr();
        __syncthreads();                     // A written + B gloads drained
        if (kt < 15) aload(kt + 1);          // prefetch under MFMA
        #pragma unroll
        for (int ks = 0; ks < 2; ++ks) {
            half8 ah[4], al[4], bh[4], bl[4];
            #pragma unroll
            for (int mi = 0; mi < 4; ++mi) {
                ah[mi] = *(const half8*)&Ah[(wm + mi * 16 + l15) * 72 + ks * 32 + l4g * 8];
                al[mi] = *(const half8*)&Al[(wm + mi * 16 + l15) * 72 + ks * 32 + l4g * 8];
            }
            #pragma unroll
            for (int ni = 0; ni < 4; ++ni) {
                int row = wn + ni * 16 + l15;
                int slot = (ks * 4 + l4g) ^ (l15 & 7);
                bh[ni] = *(const half8*)&Bhs[row * 64 + slot * 8];
                bl[ni] = *(const half8*)&Bls[row * 64 + slot * 8];
            }
            #pragma unroll
            for (int mi = 0; mi < 4; ++mi)
                #pragma unroll
                for (int ni = 0; ni < 4; ++ni) {
                    acc[mi][ni] = __builtin_amdgcn_mfma_f32_16x16x32_f16(ah[mi], bh[ni], acc[mi][ni], 0, 0, 0);
                    acc[mi][ni] = __builtin_amdgcn_mfma_f32_16x16x32_f16(ah[mi], bl[ni], acc[mi][ni], 0, 0, 0);
                    acc[mi][ni] = __builtin_amdgcn_mfma_f32_16x16x32_f16(al[mi], bh[ni], acc[mi][ni], 0, 0, 0);
                }
        }
        __syncthreads();                     // all waves done reading LDS[kt]
        if (kt < 15) bgl(kt + 1);            // single-buffered B: issue after barrier
    }

    #pragma unroll
    for (int mi = 0; mi < 4; ++mi)
        #pragma unroll
        for (int ni = 0; ni < 4; ++ni) {
            int col = bn + wn + ni * 16 + l15;
            #pragma unroll
            for (int r = 0; r < 4; ++r) {
                int row = bm + wm + mi * 16 + l4g * 4 + r;
                float val = acc[mi][ni][r];
                _Float16 hv = (_Float16)val;
                Chi[(size_t)row * DM + col] = hv;
                Clo[(size_t)row * DM + col] = (_Float16)(val - (float)hv);
            }
        }
}

// ---------------------------------------------------------------------------
// V projection: A f32 -> fp16, B via gload (double-buffered), C written as
// v^T [b][n][s] through a per-wave LDS transpose (coalesced 16B stores).
// ---------------------------------------------------------------------------
__global__ __launch_bounds__(256) void gemm_v_k(
    const float* __restrict__ A, const _Float16* __restrict__ Bt,
    _Float16* __restrict__ C)
{
    const int lid = blockIdx.x + 8 * blockIdx.y;
    const int xcd = lid & 7, k2 = lid >> 3;
    const int G = xcd * 8 + (k2 >> 3);
    const int bxv = k2 & 7, byv = G;

    __shared__ __align__(16) _Float16 SM[25600];
    _Float16* As  = SM;             // [128][72]
    _Float16* Bsb = SM + 9216;      // 2 x [128][64]

    const int t = threadIdx.x;
    const int lane = t & 63;
    const int w = t >> 6;
    const int wm = (w >> 1) * 64;
    const int wn = (w & 1) * 64;
    const int l15 = lane & 15;
    const int l4g = lane >> 4;

    const int bm = byv * 128;
    const int bn = bxv * 128;

    f32x4 acc[4][4] = {};

    const int arow = t >> 4, ac4 = t & 15;
    float4 ar[8];
    auto aload = [&](int KT) {
        #pragma unroll
        for (int i = 0; i < 8; ++i)
            ar[i] = *(const float4*)(A + (size_t)(bm + arow + 16 * i) * DM + KT * 64 + ac4 * 4);
    };
    auto awr = [&]() {
        #pragma unroll
        for (int i = 0; i < 8; ++i) {
            float4 v = ar[i];
            half4 hv;
            hv[0] = (_Float16)v.x; hv[1] = (_Float16)v.y;
            hv[2] = (_Float16)v.z; hv[3] = (_Float16)v.w;
            *(half4*)&As[(arow + 16 * i) * 72 + ac4 * 4] = hv;
        }
    };
    auto bgl = [&](int KT, int buf) {
        _Float16* Bd = Bsb + buf * 8192;
        #pragma unroll
        for (int j = 0; j < 4; ++j) {
            int rr = w * 32 + j * 8 + (lane >> 3);
            gload16(Bt + (size_t)(bn + rr) * DM + KT * 64 + (lane & 7) * 8,
                    &Bd[(w * 32 + j * 8) * 64]);
        }
    };

    aload(0);
    bgl(0, 0);
    for (int kt = 0; kt < 16; ++kt) {
        const _Float16* Bcur = Bsb + (kt & 1) * 8192;
        awr();
        __syncthreads();
        if (kt < 15) { aload(kt + 1); bgl(kt + 1, (kt + 1) & 1); }
        #pragma unroll
        for (int ks = 0; ks < 2; ++ks) {
            half8 a[4], b[4];
            #pragma unroll
            for (int mi = 0; mi < 4; ++mi)
                a[mi] = *(const half8*)&As[(wm + mi * 16 + l15) * 72 + ks * 32 + l4g * 8];
            #pragma unroll
            for (int ni = 0; ni < 4; ++ni) {
                int row = wn + ni * 16 + l15;
                int slot = (ks * 4 + l4g) ^ (l15 & 7);
                b[ni] = *(const half8*)&Bcur[row * 64 + slot * 8];
            }
            #pragma unroll
            for (int mi = 0; mi < 4; ++mi)
                #pragma unroll
                for (int ni = 0; ni < 4; ++ni)
                    acc[mi][ni] = __builtin_amdgcn_mfma_f32_16x16x32_f16(a[mi], b[ni], acc[mi][ni], 0, 0, 0);
        }
        __syncthreads();
    }

    // transposed epilogue: per-wave 64x64 tile via LDS, coalesced 16B stores
    _Float16* Tw = SM + w * 4608;   // [64][72]
    #pragma unroll
    for (int mi = 0; mi < 4; ++mi)
        #pragma unroll
        for (int ni = 0; ni < 4; ++ni)
            #pragma unroll
            for (int r = 0; r < 4; ++r)
                Tw[(ni * 16 + l15) * 72 + mi * 16 + l4g * 4 + r] = (_Float16)acc[mi][ni][r];
    __syncthreads();
    {
        const int mg0 = bm + wm;
        const int b = mg0 >> 10, s0 = mg0 & 1023;
        _Float16* op = C + ((size_t)b * DM + (bn + wn + lane)) * S_ + s0;
        #pragma unroll
        for (int c8 = 0; c8 < 8; ++c8)
            *(half8*)(op + c8 * 8) = *(const half8*)&Tw[lane * 72 + c8 * 8];
    }
}

// ---------------------------------------------------------------------------
// Output projection: A fp16 reg-staged, B via gload (double-buffered),
// C f32 + bias, XCD-group remap.
// ---------------------------------------------------------------------------
__global__ __launch_bounds__(256) void gemm_out_k(
    const _Float16* __restrict__ A, const _Float16* __restrict__ Bt,
    float* __restrict__ C, const float* __restrict__ bias)
{
    const int lid = blockIdx.x + 8 * blockIdx.y;
    const int xcd = lid & 7, k2 = lid >> 3;
    const int G = xcd * 8 + (k2 >> 3);
    const int bxv = k2 & 7, byv = G;

    __shared__ __align__(16) _Float16 SM[25600];
    _Float16* As  = SM;             // [128][72]
    _Float16* Bsb = SM + 9216;      // 2 x [128][64]

    const int t = threadIdx.x;
    const int lane = t & 63;
    const int w = t >> 6;
    const int wm = (w >> 1) * 64;
    const int wn = (w & 1) * 64;
    const int l15 = lane & 15;
    const int l4g = lane >> 4;

    const int bm = byv * 128;
    const int bn = bxv * 128;

    f32x4 acc[4][4] = {};

    uint4 arr[4];
    auto aload = [&](int KT) {
        #pragma unroll
        for (int i = 0; i < 4; ++i)
            arr[i] = *(const uint4*)(A + (size_t)(bm + (t >> 3) + 32 * i) * DM + KT * 64 + (t & 7) * 8);
    };
    auto awr = [&]() {
        #pragma unroll
        for (int i = 0; i < 4; ++i)
            *(uint4*)&As[((t >> 3) + 32 * i) * 72 + (t & 7) * 8] = arr[i];
    };
    auto bgl = [&](int KT, int buf) {
        _Float16* Bd = Bsb + buf * 8192;
        #pragma unroll
        for (int j = 0; j < 4; ++j) {
            int rr = w * 32 + j * 8 + (lane >> 3);
            gload16(Bt + (size_t)(bn + rr) * DM + KT * 64 + (lane & 7) * 8,
                    &Bd[(w * 32 + j * 8) * 64]);
        }
    };

    aload(0);
    bgl(0, 0);
    for (int kt = 0; kt < 16; ++kt) {
        const _Float16* Bcur = Bsb + (kt & 1) * 8192;
        awr();
        __syncthreads();
        if (kt < 15) { aload(kt + 1); bgl(kt + 1, (kt + 1) & 1); }
        #pragma unroll
        for (int ks = 0; ks < 2; ++ks) {
            half8 a[4], b[4];
            #pragma unroll
            for (int mi = 0; mi < 4; ++mi)
                a[mi] = *(const half8*)&As[(wm + mi * 16 + l15) * 72 + ks * 32 + l4g * 8];
            #pragma unroll
            for (int ni = 0; ni < 4; ++ni) {
                int row = wn + ni * 16 + l15;
                int slot = (ks * 4 + l4g) ^ (l15 & 7);
                b[ni] = *(const half8*)&Bcur[row * 64 + slot * 8];
            }
            #pragma unroll
            for (int mi = 0; mi < 4; ++mi)
                #pragma unroll
                for (int ni = 0; ni < 4; ++ni)
                    acc[mi][ni] = __builtin_amdgcn_mfma_f32_16x16x32_f16(a[mi], b[ni], acc[mi][ni], 0, 0, 0);
        }
        __syncthreads();
    }

    #pragma unroll
    for (int mi = 0; mi < 4; ++mi)
        #pragma unroll
        for (int ni = 0; ni < 4; ++ni) {
            int col = bn + wn + ni * 16 + l15;
            #pragma unroll
            for (int r = 0; r < 4; ++r) {
                int row = bm + wm + mi * 16 + l4g * 4 + r;
                C[(size_t)row * DM + col] = acc[mi][ni][r] + bias[col];
            }
        }
}

// ---------------------------------------------------------------------------
// Flash attention — byte-identical to round 4 (validated).
// ---------------------------------------------------------------------------
__global__ __launch_bounds__(256) void attn_k(
    const _Float16* __restrict__ qhg, const _Float16* __restrict__ qlg,
    const _Float16* __restrict__ khg, const _Float16* __restrict__ klg,
    const _Float16* __restrict__ vtg, const unsigned char* __restrict__ maskg,
    const unsigned char* __restrict__ scanp, _Float16* __restrict__ ho)
{
    __shared__ __align__(16) _Float16 Kh[64][72];
    __shared__ __align__(16) _Float16 Kl[64][72];
    __shared__ __align__(16) _Float16 Vt[64][72];

    const int t = threadIdx.x;
    const int lane = t & 63;
    const int w = t >> 6;
    const int l31 = lane & 31;
    const int hi = lane >> 5;

    const int j = blockIdx.y + 16 * blockIdx.z;          // 0..127
    const int head = 16 * blockIdx.x + (j >> 3);         // 0..127
    const int qt = j & 7;
    const int h = head & 15;
    const int b = head >> 4;

    const int colbase = h * DH;
    const int qrow = qt * 128 + w * 32 + l31;

    half8 qfh[4], qfl[4];
    {
        const size_t base = ((size_t)b * S_ + qrow) * DM + colbase;
        #pragma unroll
        for (int ds = 0; ds < 4; ++ds) {
            qfh[ds] = *(const half8*)(qhg + base + ds * 16 + hi * 8);
            qfl[ds] = *(const half8*)(qlg + base + ds * 16 + hi * 8);
        }
    }

    float m_q = -1e30f, ls = 0.0f;
    f32x16 accO0 = {};
    f32x16 accO1 = {};

    const int r0 = t >> 3;
    const int c0 = (t & 7) * 8;
    const _Float16* kph = khg + ((size_t)b * S_) * DM + colbase;
    const _Float16* kpl = klg + ((size_t)b * S_) * DM + colbase;
    const _Float16* vp  = vtg + ((size_t)b * DM + colbase) * S_;
    const unsigned char* sc0 = scanp + (b * 16 + 2 * qt) * 16;
    const unsigned char* sc1 = scanp + (b * 16 + 2 * qt + 1) * 16;

    uint4 akh0, akh1, akl0, akl1, av0, av1;
#define ALOAD(KT) do { \
        akh0 = *(const uint4*)(kph + (size_t)((KT) * 64 + r0) * DM + c0);       \
        akh1 = *(const uint4*)(kph + (size_t)((KT) * 64 + 32 + r0) * DM + c0);  \
        akl0 = *(const uint4*)(kpl + (size_t)((KT) * 64 + r0) * DM + c0);       \
        akl1 = *(const uint4*)(kpl + (size_t)((KT) * 64 + 32 + r0) * DM + c0);  \
        av0  = *(const uint4*)(vp + (size_t)r0 * S_ + (KT) * 64 + c0);          \
        av1  = *(const uint4*)(vp + (size_t)(32 + r0) * S_ + (KT) * 64 + c0);   \
    } while (0)
#define AWRITE() do { \
        *(uint4*)&Kh[r0][c0] = akh0; *(uint4*)&Kh[32 + r0][c0] = akh1; \
        *(uint4*)&Kl[r0][c0] = akl0; *(uint4*)&Kl[32 + r0][c0] = akl1; \
        *(uint4*)&Vt[r0][c0] = av0;  *(uint4*)&Vt[32 + r0][c0] = av1;  \
    } while (0)

    ALOAD(0);
    AWRITE();
    int msk = sc0[0] | sc1[0];

    const float SC = 0.125f * 1.44269504089f;

    for (int kt = 0; kt < 16; ++kt) {
        __syncthreads();
        const int mskcur = msk;
        if (kt < 15) {
            ALOAD(kt + 1);
            msk = sc0[kt + 1] | sc1[kt + 1];
        }

        f32x16 sa0 = {}, sa1 = {};
        #pragma unroll
        for (int ds = 0; ds < 4; ++ds) {
            half8 kh0 = *(const half8*)&Kh[l31][ds * 16 + hi * 8];
            half8 kl0 = *(const half8*)&Kl[l31][ds * 16 + hi * 8];
            half8 kh1 = *(const half8*)&Kh[32 + l31][ds * 16 + hi * 8];
            half8 kl1 = *(const half8*)&Kl[32 + l31][ds * 16 + hi * 8];
            sa0 = __builtin_amdgcn_mfma_f32_32x32x16_f16(kh0, qfh[ds], sa0, 0, 0, 0);
            sa0 = __builtin_amdgcn_mfma_f32_32x32x16_f16(kh0, qfl[ds], sa0, 0, 0, 0);
            sa0 = __builtin_amdgcn_mfma_f32_32x32x16_f16(kl0, qfh[ds], sa0, 0, 0, 0);
            sa1 = __builtin_amdgcn_mfma_f32_32x32x16_f16(kh1, qfh[ds], sa1, 0, 0, 0);
            sa1 = __builtin_amdgcn_mfma_f32_32x32x16_f16(kh1, qfl[ds], sa1, 0, 0, 0);
            sa1 = __builtin_amdgcn_mfma_f32_32x32x16_f16(kl1, qfh[ds], sa1, 0, 0, 0);
        }
        #pragma unroll
        for (int e = 0; e < 16; ++e) { sa0[e] *= SC; sa1[e] *= SC; }

        if (mskcur) {
            const unsigned char* mrow = maskg + ((size_t)b * S_ + qrow) * S_ + kt * 64;
            #pragma unroll
            for (int e = 0; e < 16; ++e) {
                int kl_ = (e & 3) + 8 * (e >> 2) + 4 * hi;
                if (mrow[kl_]) sa0[e] = -1e9f;
                if (mrow[32 + kl_]) sa1[e] = -1e9f;
            }
        }

        float rm = sa0[0];
        #pragma unroll
        for (int e = 1; e < 16; ++e) rm = fmaxf(rm, sa0[e]);
        #pragma unroll
        for (int e = 0; e < 16; ++e) rm = fmaxf(rm, sa1[e]);
        rm = fmaxf(rm, __shfl_xor(rm, 32));
        const float mn = fmaxf(m_q, rm);
        const float sfac = exp2f(m_q - mn);
        m_q = mn;
        float rs = 0.0f;
        #pragma unroll
        for (int e = 0; e < 16; ++e) { sa0[e] = exp2f(sa0[e] - mn); rs += sa0[e]; }
        #pragma unroll
        for (int e = 0; e < 16; ++e) { sa1[e] = exp2f(sa1[e] - mn); rs += sa1[e]; }
        rs += __shfl_xor(rs, 32);
        ls = ls * sfac + rs;
        #pragma unroll
        for (int e = 0; e < 16; ++e) { accO0[e] *= sfac; accO1[e] *= sfac; }

        half8 pf[4];
        {
            uint c0_ = pkh(sa0[0], sa0[1]),  c1_ = pkh(sa0[2], sa0[3]);
            uint c2_ = pkh(sa0[4], sa0[5]),  c3_ = pkh(sa0[6], sa0[7]);
            uint c4_ = pkh(sa0[8], sa0[9]),  c5_ = pkh(sa0[10], sa0[11]);
            uint c6_ = pkh(sa0[12], sa0[13]), c7_ = pkh(sa0[14], sa0[15]);
            PSWAP(c0_, c2_); PSWAP(c1_, c3_);
            PSWAP(c4_, c6_); PSWAP(c5_, c7_);
            uint4 u0 = {c0_, c1_, c2_, c3_}, u1 = {c4_, c5_, c6_, c7_};
            pf[0] = __builtin_bit_cast(half8, u0);
            pf[1] = __builtin_bit_cast(half8, u1);
        }
        {
            uint c0_ = pkh(sa1[0], sa1[1]),  c1_ = pkh(sa1[2], sa1[3]);
            uint c2_ = pkh(sa1[4], sa1[5]),  c3_ = pkh(sa1[6], sa1[7]);
            uint c4_ = pkh(sa1[8], sa1[9]),  c5_ = pkh(sa1[10], sa1[11]);
            uint c6_ = pkh(sa1[12], sa1[13]), c7_ = pkh(sa1[14], sa1[15]);
            PSWAP(c0_, c2_); PSWAP(c1_, c3_);
            PSWAP(c4_, c6_); PSWAP(c5_, c7_);
            uint4 u0 = {c0_, c1_, c2_, c3_}, u1 = {c4_, c5_, c6_, c7_};
            pf[2] = __builtin_bit_cast(half8, u0);
            pf[3] = __builtin_bit_cast(half8, u1);
        }
        #pragma unroll
        for (int kc = 0; kc < 4; ++kc) {
            half8 vf0 = *(const half8*)&Vt[l31][kc * 16 + hi * 8];
            half8 vf1 = *(const half8*)&Vt[32 + l31][kc * 16 + hi * 8];
            accO0 = __builtin_amdgcn_mfma_f32_32x32x16_f16(vf0, pf[kc], accO0, 0, 0, 0);
            accO1 = __builtin_amdgcn_mfma_f32_32x32x16_f16(vf1, pf[kc], accO1, 0, 0, 0);
        }

        __syncthreads();
        if (kt < 15) AWRITE();
    }
#undef ALOAD
#undef AWRITE

    const float inv = 1.0f / ls;
    _Float16* orow = ho + ((size_t)b * S_ + qrow) * DM + colbase;
    #pragma unroll
    for (int g2 = 0; g2 < 4; ++g2) {
        half4 hv0, hv1;
        #pragma unroll
        for (int e = 0; e < 4; ++e) {
            hv0[e] = (_Float16)(accO0[g2 * 4 + e] * inv);
            hv1[e] = (_Float16)(accO1[g2 * 4 + e] * inv);
        }
        *(half4*)(orow + g2 * 8 + hi * 4) = hv0;
        *(half4*)(orow + 32 + g2 * 8 + hi * 4) = hv1;
    }
}

// ---------------------------------------------------------------------------
extern "C" void kernel_launch(void* const* d_in, const int* in_sizes, int n_in,
                              void* d_out, int out_size, void* d_ws, size_t ws_size,
                              hipStream_t stream)
{
    const float* Qs = (const float*)d_in[0];
    const float* Ks = (const float*)d_in[1];
    const float* Vs = (const float*)d_in[2];
    const unsigned char* mask = (const unsigned char*)d_in[3];
    const float* WQ = (const float*)d_in[4];
    const float* WK = (const float*)d_in[5];
    const float* WV = (const float*)d_in[6];
    const float* WO = (const float*)d_in[7];
    const float* bo = (const float*)d_in[8];

    char* ws = (char*)d_ws;
    const size_t MB = 1024 * 1024;
    _Float16* wqh = (_Float16*)(ws + 0 * MB);
    _Float16* wql = (_Float16*)(ws + 2 * MB);
    _Float16* wkh = (_Float16*)(ws + 4 * MB);
    _Float16* wkl = (_Float16*)(ws + 6 * MB);
    _Float16* wv  = (_Float16*)(ws + 8 * MB);
    _Float16* wo  = (_Float16*)(ws + 10 * MB);
    _Float16* qhi = (_Float16*)(ws + 12 * MB);
    _Float16* qlo = (_Float16*)(ws + 28 * MB);
    _Float16* khi = (_Float16*)(ws + 44 * MB);
    _Float16* klo = (_Float16*)(ws + 60 * MB);
    _Float16* vt  = (_Float16*)(ws + 76 * MB);
    _Float16* hh  = (_Float16*)(ws + 92 * MB);
    unsigned char* scan = (unsigned char*)(ws + 108 * MB);

    packw_k<<<dim3(16, 16), 256, 0, stream>>>(WQ, WK, WV, wqh, wql, wkh, wkl, wv);
    packo_k<<<512, 256, 0, stream>>>(WO, wo);
    scan_k<<<dim3(16, 16, 8), 256, 0, stream>>>(mask, scan);

    gemm_split_k<<<dim3(8, 64, 2), 256, 0, stream>>>(
        Qs, Ks, wqh, wql, wkh, wkl, qhi, qlo, khi, klo);

    gemm_v_k<<<dim3(8, 64), 256, 0, stream>>>(Vs, wv, vt);

    attn_k<<<dim3(8, 16, 8), 256, 0, stream>>>(qhi, qlo, khi, klo, vt, mask, scan, hh);

    gemm_out_k<<<dim3(8, 64), 256, 0, stream>>>(hh, wo, (float*)d_out, bo);
}

// Round 7
// 305.733 us; speedup vs baseline: 1.2159x; 1.0143x over previous
//
#include <hip/hip_runtime.h>

#define DM 1024
#define H_ 16
#define DH 64
#define B_ 8
#define S_ 1024

typedef _Float16 half8 __attribute__((ext_vector_type(8)));
typedef _Float16 half4 __attribute__((ext_vector_type(4)));
typedef __fp16 fp16x2 __attribute__((ext_vector_type(2)));
typedef float f32x4 __attribute__((ext_vector_type(4)));
typedef float f32x16 __attribute__((ext_vector_type(16)));
typedef unsigned int uint;

// packed f32x2 -> fp16x2 (single v_cvt_pkrtz_f16_f32)
static __device__ __forceinline__ uint pkrtz(float a, float b) {
    fp16x2 h = __builtin_amdgcn_cvt_pkrtz(a, b);
    return __builtin_bit_cast(uint, h);
}
// v_permlane32_swap_b32 d, s: d.lanes[32:63] <-> s.lanes[0:31]
#define PSWAP(d, s) asm volatile("v_permlane32_swap_b32 %0, %1" : "+v"(d), "+v"(s))

// async global->LDS, 16 B per lane; LDS dest base must be wave-uniform
static __device__ __forceinline__ void gload16(const _Float16* g, _Float16* l) {
    __builtin_amdgcn_global_load_lds(
        (const __attribute__((address_space(1))) unsigned int*)(const void*)g,
        (__attribute__((address_space(3))) unsigned int*)(void*)l,
        16, 0, 0);
}

// ---------------------------------------------------------------------------
// Pack projection weights with LDS transpose. Output rows n=h*64+l, cols k,
// fp16 (hi/lo for WQ,WK), 16B-chunk XOR: logical chunk c at phys (c&~7)|((c&7)^(n&7)).
// ---------------------------------------------------------------------------
__global__ __launch_bounds__(256) void packw_k(
    const float* __restrict__ WQ, const float* __restrict__ WK,
    const float* __restrict__ WV,
    _Float16* __restrict__ wqh, _Float16* __restrict__ wql,
    _Float16* __restrict__ wkh, _Float16* __restrict__ wkl,
    _Float16* __restrict__ wv)
{
    __shared__ __align__(16) _Float16 Lh[64][72];
    __shared__ __align__(16) _Float16 Ll[64][72];
    const int t = threadIdx.x;
    const int kb = blockIdx.x;   // k-block of 64
    const int h  = blockIdx.y;   // head

    #pragma unroll
    for (int s = 0; s < 3; ++s) {
        const float* W = (s == 0) ? WQ : ((s == 1) ? WK : WV);
        const int krow = t >> 2, lc = t & 3;
        const float* rp = W + (((size_t)h * 1024 + kb * 64 + krow) * 64 + lc * 16);
        #pragma unroll
        for (int q4 = 0; q4 < 4; ++q4) {
            float4 f = ((const float4*)rp)[q4];
            float vv0 = f.x, vv1 = f.y, vv2 = f.z, vv3 = f.w;
            int l0 = lc * 16 + q4 * 4;
            _Float16 h0 = (_Float16)vv0; Lh[l0 + 0][krow] = h0; Ll[l0 + 0][krow] = (_Float16)(vv0 - (float)h0);
            _Float16 h1 = (_Float16)vv1; Lh[l0 + 1][krow] = h1; Ll[l0 + 1][krow] = (_Float16)(vv1 - (float)h1);
            _Float16 h2 = (_Float16)vv2; Lh[l0 + 2][krow] = h2; Ll[l0 + 2][krow] = (_Float16)(vv2 - (float)h2);
            _Float16 h3 = (_Float16)vv3; Lh[l0 + 3][krow] = h3; Ll[l0 + 3][krow] = (_Float16)(vv3 - (float)h3);
        }
        __syncthreads();
        const int l = t >> 2, pc = t & 3;
        #pragma unroll
        for (int hp = 0; hp < 2; ++hp) {
            int p = pc + 4 * hp;
            int lc2 = p ^ (l & 7);
            half8 vh = *(const half8*)&Lh[l][lc2 * 8];
            half8 vl = *(const half8*)&Ll[l][lc2 * 8];
            size_t off = (size_t)(h * 64 + l) * DM + kb * 64 + p * 8;
            if (s == 0) { *(half8*)(wqh + off) = vh; *(half8*)(wql + off) = vl; }
            else if (s == 1) { *(half8*)(wkh + off) = vh; *(half8*)(wkl + off) = vl; }
            else { *(half8*)(wv + off) = vh; }
        }
        __syncthreads();
    }
}

// ---------------------------------------------------------------------------
// Pack W_out: already [n][k]; fp16 convert + chunk XOR.
// ---------------------------------------------------------------------------
__global__ __launch_bounds__(256) void packo_k(
    const float* __restrict__ WO, _Float16* __restrict__ wo)
{
    int idx8 = blockIdx.x * 256 + threadIdx.x;
    int n = idx8 >> 7;
    int c = idx8 & 127;
    int p = (c & ~7) | ((c & 7) ^ (n & 7));
    const float* rp = WO + ((size_t)n * DM + c * 8);
    float4 a = ((const float4*)rp)[0];
    float4 b = ((const float4*)rp)[1];
    half8 v;
    v[0] = (_Float16)a.x; v[1] = (_Float16)a.y; v[2] = (_Float16)a.z; v[3] = (_Float16)a.w;
    v[4] = (_Float16)b.x; v[5] = (_Float16)b.y; v[6] = (_Float16)b.z; v[7] = (_Float16)b.w;
    *(half8*)(wo + (size_t)n * DM + p * 8) = v;
}

// ---------------------------------------------------------------------------
// Mask pre-scan (unchanged, validated).
// ---------------------------------------------------------------------------
__global__ __launch_bounds__(256) void scan_k(
    const unsigned char* __restrict__ mask, unsigned char* __restrict__ scan)
{
    __shared__ int s_red[4];
    const int t = threadIdx.x;
    const int q64 = blockIdx.x, k64 = blockIdx.y, b = blockIdx.z;
    uint4 mv = *(const uint4*)(mask + ((size_t)b * S_ + q64 * 64 + (t >> 2)) * S_ + k64 * 64 + (t & 3) * 16);
    int a = (mv.x | mv.y | mv.z | mv.w) != 0;
    unsigned long long bal = __ballot(a);
    if ((t & 63) == 0) s_red[t >> 6] = (bal != 0ull);
    __syncthreads();
    if (t == 0)
        scan[(b * 16 + q64) * 16 + k64] =
            (unsigned char)(s_red[0] | s_red[1] | s_red[2] | s_red[3]);
}

// ---------------------------------------------------------------------------
// Split-precision GEMM (Q,K proj), 512 threads / 8 waves, each wave 32x64 out.
// A f32 reg-staged -> hi/lo in XOR-chunk LDS [128][64] (2-way conflict free);
// B via global_load_lds from pre-XOR-packed weights. LDS 64 KB -> 2 blocks/CU
// = 16 waves/CU. XCD-group remap keeps same-A-panel blocks on one L2.
// ---------------------------------------------------------------------------
__global__ __launch_bounds__(512) void gemm_split_k(
    const float* __restrict__ A0, const float* __restrict__ A1,
    const _Float16* __restrict__ Bh0, const _Float16* __restrict__ Bl0,
    const _Float16* __restrict__ Bh1, const _Float16* __restrict__ Bl1,
    _Float16* __restrict__ Chi0, _Float16* __restrict__ Clo0,
    _Float16* __restrict__ Chi1, _Float16* __restrict__ Clo1)
{
    const int lid = blockIdx.x + 8 * blockIdx.y + 512 * blockIdx.z;
    const int xcd = lid & 7, k2 = lid >> 3;
    const int G = xcd * 16 + (k2 >> 3);
    const int bxv = k2 & 7, byv = G & 63, z = G >> 6;

    const float* A = z ? A1 : A0;
    const _Float16* Bh = z ? Bh1 : Bh0;
    const _Float16* Bl = z ? Bl1 : Bl0;
    _Float16* Chi = z ? Chi1 : Chi0;
    _Float16* Clo = z ? Clo1 : Clo0;

    __shared__ __align__(16) _Float16 SM[32768];   // 64 KB
    _Float16* Ah  = SM;                 // [128][64] XOR-chunk
    _Float16* Al  = SM + 8192;
    _Float16* Bhs = SM + 16384;         // [128][64] linear dest (pre-XOR'd source)
    _Float16* Bls = SM + 24576;

    const int t = threadIdx.x;
    const int lane = t & 63;
    const int w = t >> 6;               // 0..7
    const int wm = (w >> 1) * 32;
    const int wn = (w & 1) * 64;
    const int l15 = lane & 15;
    const int l4g = lane >> 4;

    const int bm = byv * 128;
    const int bn = bxv * 128;

    f32x4 acc[2][4] = {};

    float4 ar[4];
    auto aload = [&](int KT) {
        #pragma unroll
        for (int i = 0; i < 4; ++i)
            ar[i] = *(const float4*)(A + (size_t)(bm + (t >> 4) + 32 * i) * DM + KT * 64 + (t & 15) * 4);
    };
    auto awr = [&]() {
        #pragma unroll
        for (int i = 0; i < 4; ++i) {
            int row = (t >> 4) + 32 * i;
            int c4 = t & 15;
            float4 v = ar[i];
            half4 hv, lv;
            hv[0] = (_Float16)v.x; lv[0] = (_Float16)(v.x - (float)hv[0]);
            hv[1] = (_Float16)v.y; lv[1] = (_Float16)(v.y - (float)hv[1]);
            hv[2] = (_Float16)v.z; lv[2] = (_Float16)(v.z - (float)hv[2]);
            hv[3] = (_Float16)v.w; lv[3] = (_Float16)(v.w - (float)hv[3]);
            int off = row * 64 + (((c4 >> 1) ^ (row & 7)) * 8) + (c4 & 1) * 4;
            *(half4*)&Ah[off] = hv;
            *(half4*)&Al[off] = lv;
        }
    };
    auto bgl = [&](int KT) {
        #pragma unroll
        for (int j = 0; j < 2; ++j) {
            int rr = w * 16 + j * 8 + (lane >> 3);
            const size_t so = (size_t)(bn + rr) * DM + KT * 64 + (lane & 7) * 8;
            gload16(Bh + so, &Bhs[(w * 16 + j * 8) * 64]);
            gload16(Bl + so, &Bls[(w * 16 + j * 8) * 64]);
        }
    };

    aload(0);
    bgl(0);
    for (int kt = 0; kt < 16; ++kt) {
        awr();
        __syncthreads();                 // A written + B gloads drained
        if (kt < 15) aload(kt + 1);      // prefetch under MFMA
        #pragma unroll
        for (int ks = 0; ks < 2; ++ks) {
            half8 ah[2], al[2], bh[4], bl[4];
            const int slotx = (ks * 4 + l4g);
            #pragma unroll
            for (int mi = 0; mi < 2; ++mi) {
                int r = wm + mi * 16 + l15;
                int off = r * 64 + (slotx ^ (l15 & 7)) * 8;
                ah[mi] = *(const half8*)&Ah[off];
                al[mi] = *(const half8*)&Al[off];
            }
            #pragma unroll
            for (int ni = 0; ni < 4; ++ni) {
                int r = wn + ni * 16 + l15;
                int off = r * 64 + (slotx ^ (l15 & 7)) * 8;
                bh[ni] = *(const half8*)&Bhs[off];
                bl[ni] = *(const half8*)&Bls[off];
            }
            #pragma unroll
            for (int mi = 0; mi < 2; ++mi)
                #pragma unroll
                for (int ni = 0; ni < 4; ++ni) {
                    acc[mi][ni] = __builtin_amdgcn_mfma_f32_16x16x32_f16(ah[mi], bh[ni], acc[mi][ni], 0, 0, 0);
                    acc[mi][ni] = __builtin_amdgcn_mfma_f32_16x16x32_f16(ah[mi], bl[ni], acc[mi][ni], 0, 0, 0);
                    acc[mi][ni] = __builtin_amdgcn_mfma_f32_16x16x32_f16(al[mi], bh[ni], acc[mi][ni], 0, 0, 0);
                }
        }
        __syncthreads();                 // all waves done reading LDS[kt]
        if (kt < 15) bgl(kt + 1);
    }

    #pragma unroll
    for (int mi = 0; mi < 2; ++mi)
        #pragma unroll
        for (int ni = 0; ni < 4; ++ni) {
            int col = bn + wn + ni * 16 + l15;
            #pragma unroll
            for (int r = 0; r < 4; ++r) {
                int row = bm + wm + mi * 16 + l4g * 4 + r;
                float val = acc[mi][ni][r];
                _Float16 hv = (_Float16)val;
                Chi[(size_t)row * DM + col] = hv;
                Clo[(size_t)row * DM + col] = (_Float16)(val - (float)hv);
            }
        }
}

// ---------------------------------------------------------------------------
// V projection: unchanged from r5 (validated).
// ---------------------------------------------------------------------------
__global__ __launch_bounds__(256) void gemm_v_k(
    const float* __restrict__ A, const _Float16* __restrict__ Bt,
    _Float16* __restrict__ C)
{
    const int lid = blockIdx.x + 8 * blockIdx.y;
    const int xcd = lid & 7, k2 = lid >> 3;
    const int G = xcd * 8 + (k2 >> 3);
    const int bxv = k2 & 7, byv = G;

    __shared__ __align__(16) _Float16 SM[25600];
    _Float16* As  = SM;             // [128][72]
    _Float16* Bsb = SM + 9216;      // 2 x [128][64]

    const int t = threadIdx.x;
    const int lane = t & 63;
    const int w = t >> 6;
    const int wm = (w >> 1) * 64;
    const int wn = (w & 1) * 64;
    const int l15 = lane & 15;
    const int l4g = lane >> 4;

    const int bm = byv * 128;
    const int bn = bxv * 128;

    f32x4 acc[4][4] = {};

    const int arow = t >> 4, ac4 = t & 15;
    float4 ar[8];
    auto aload = [&](int KT) {
        #pragma unroll
        for (int i = 0; i < 8; ++i)
            ar[i] = *(const float4*)(A + (size_t)(bm + arow + 16 * i) * DM + KT * 64 + ac4 * 4);
    };
    auto awr = [&]() {
        #pragma unroll
        for (int i = 0; i < 8; ++i) {
            float4 v = ar[i];
            half4 hv;
            hv[0] = (_Float16)v.x; hv[1] = (_Float16)v.y;
            hv[2] = (_Float16)v.z; hv[3] = (_Float16)v.w;
            *(half4*)&As[(arow + 16 * i) * 72 + ac4 * 4] = hv;
        }
    };
    auto bgl = [&](int KT, int buf) {
        _Float16* Bd = Bsb + buf * 8192;
        #pragma unroll
        for (int j = 0; j < 4; ++j) {
            int rr = w * 32 + j * 8 + (lane >> 3);
            gload16(Bt + (size_t)(bn + rr) * DM + KT * 64 + (lane & 7) * 8,
                    &Bd[(w * 32 + j * 8) * 64]);
        }
    };

    aload(0);
    bgl(0, 0);
    for (int kt = 0; kt < 16; ++kt) {
        const _Float16* Bcur = Bsb + (kt & 1) * 8192;
        awr();
        __syncthreads();
        if (kt < 15) { aload(kt + 1); bgl(kt + 1, (kt + 1) & 1); }
        #pragma unroll
        for (int ks = 0; ks < 2; ++ks) {
            half8 a[4], b[4];
            #pragma unroll
            for (int mi = 0; mi < 4; ++mi)
                a[mi] = *(const half8*)&As[(wm + mi * 16 + l15) * 72 + ks * 32 + l4g * 8];
            #pragma unroll
            for (int ni = 0; ni < 4; ++ni) {
                int row = wn + ni * 16 + l15;
                int slot = (ks * 4 + l4g) ^ (l15 & 7);
                b[ni] = *(const half8*)&Bcur[row * 64 + slot * 8];
            }
            #pragma unroll
            for (int mi = 0; mi < 4; ++mi)
                #pragma unroll
                for (int ni = 0; ni < 4; ++ni)
                    acc[mi][ni] = __builtin_amdgcn_mfma_f32_16x16x32_f16(a[mi], b[ni], acc[mi][ni], 0, 0, 0);
        }
        __syncthreads();
    }

    _Float16* Tw = SM + w * 4608;   // [64][72]
    #pragma unroll
    for (int mi = 0; mi < 4; ++mi)
        #pragma unroll
        for (int ni = 0; ni < 4; ++ni)
            #pragma unroll
            for (int r = 0; r < 4; ++r)
                Tw[(ni * 16 + l15) * 72 + mi * 16 + l4g * 4 + r] = (_Float16)acc[mi][ni][r];
    __syncthreads();
    {
        const int mg0 = bm + wm;
        const int b = mg0 >> 10, s0 = mg0 & 1023;
        _Float16* op = C + ((size_t)b * DM + (bn + wn + lane)) * S_ + s0;
        #pragma unroll
        for (int c8 = 0; c8 < 8; ++c8)
            *(half8*)(op + c8 * 8) = *(const half8*)&Tw[lane * 72 + c8 * 8];
    }
}

// ---------------------------------------------------------------------------
// Output projection: unchanged from r5 (validated).
// ---------------------------------------------------------------------------
__global__ __launch_bounds__(256) void gemm_out_k(
    const _Float16* __restrict__ A, const _Float16* __restrict__ Bt,
    float* __restrict__ C, const float* __restrict__ bias)
{
    const int lid = blockIdx.x + 8 * blockIdx.y;
    const int xcd = lid & 7, k2 = lid >> 3;
    const int G = xcd * 8 + (k2 >> 3);
    const int bxv = k2 & 7, byv = G;

    __shared__ __align__(16) _Float16 SM[25600];
    _Float16* As  = SM;
    _Float16* Bsb = SM + 9216;

    const int t = threadIdx.x;
    const int lane = t & 63;
    const int w = t >> 6;
    const int wm = (w >> 1) * 64;
    const int wn = (w & 1) * 64;
    const int l15 = lane & 15;
    const int l4g = lane >> 4;

    const int bm = byv * 128;
    const int bn = bxv * 128;

    f32x4 acc[4][4] = {};

    uint4 arr[4];
    auto aload = [&](int KT) {
        #pragma unroll
        for (int i = 0; i < 4; ++i)
            arr[i] = *(const uint4*)(A + (size_t)(bm + (t >> 3) + 32 * i) * DM + KT * 64 + (t & 7) * 8);
    };
    auto awr = [&]() {
        #pragma unroll
        for (int i = 0; i < 4; ++i)
            *(uint4*)&As[((t >> 3) + 32 * i) * 72 + (t & 7) * 8] = arr[i];
    };
    auto bgl = [&](int KT, int buf) {
        _Float16* Bd = Bsb + buf * 8192;
        #pragma unroll
        for (int j = 0; j < 4; ++j) {
            int rr = w * 32 + j * 8 + (lane >> 3);
            gload16(Bt + (size_t)(bn + rr) * DM + KT * 64 + (lane & 7) * 8,
                    &Bd[(w * 32 + j * 8) * 64]);
        }
    };

    aload(0);
    bgl(0, 0);
    for (int kt = 0; kt < 16; ++kt) {
        const _Float16* Bcur = Bsb + (kt & 1) * 8192;
        awr();
        __syncthreads();
        if (kt < 15) { aload(kt + 1); bgl(kt + 1, (kt + 1) & 1); }
        #pragma unroll
        for (int ks = 0; ks < 2; ++ks) {
            half8 a[4], b[4];
            #pragma unroll
            for (int mi = 0; mi < 4; ++mi)
                a[mi] = *(const half8*)&As[(wm + mi * 16 + l15) * 72 + ks * 32 + l4g * 8];
            #pragma unroll
            for (int ni = 0; ni < 4; ++ni) {
                int row = wn + ni * 16 + l15;
                int slot = (ks * 4 + l4g) ^ (l15 & 7);
                b[ni] = *(const half8*)&Bcur[row * 64 + slot * 8];
            }
            #pragma unroll
            for (int mi = 0; mi < 4; ++mi)
                #pragma unroll
                for (int ni = 0; ni < 4; ++ni)
                    acc[mi][ni] = __builtin_amdgcn_mfma_f32_16x16x32_f16(a[mi], b[ni], acc[mi][ni], 0, 0, 0);
        }
        __syncthreads();
    }

    #pragma unroll
    for (int mi = 0; mi < 4; ++mi)
        #pragma unroll
        for (int ni = 0; ni < 4; ++ni) {
            int col = bn + wn + ni * 16 + l15;
            #pragma unroll
            for (int r = 0; r < 4; ++r) {
                int row = bm + wm + mi * 16 + l4g * 4 + r;
                C[(size_t)row * DM + col] = acc[mi][ni][r] + bias[col];
            }
        }
}

// ---------------------------------------------------------------------------
// Flash attention, 32x32 swapped-operand. r4-validated structure with VALU
// trims: raw-score-domain online softmax (scale folded into exp2 via fma),
// defer-max (T13, THR_raw = 8/SC), cvt_pkrtz packing, setprio around MFMA.
// ---------------------------------------------------------------------------
__global__ __launch_bounds__(256) void attn_k(
    const _Float16* __restrict__ qhg, const _Float16* __restrict__ qlg,
    const _Float16* __restrict__ khg, const _Float16* __restrict__ klg,
    const _Float16* __restrict__ vtg, const unsigned char* __restrict__ maskg,
    const unsigned char* __restrict__ scanp, _Float16* __restrict__ ho)
{
    __shared__ __align__(16) _Float16 Kh[64][72];
    __shared__ __align__(16) _Float16 Kl[64][72];
    __shared__ __align__(16) _Float16 Vt[64][72];

    const int t = threadIdx.x;
    const int lane = t & 63;
    const int w = t >> 6;
    const int l31 = lane & 31;
    const int hi = lane >> 5;

    const int j = blockIdx.y + 16 * blockIdx.z;          // 0..127
    const int head = 16 * blockIdx.x + (j >> 3);         // 0..127
    const int qt = j & 7;
    const int h = head & 15;
    const int b = head >> 4;

    const int colbase = h * DH;
    const int qrow = qt * 128 + w * 32 + l31;

    half8 qfh[4], qfl[4];
    {
        const size_t base = ((size_t)b * S_ + qrow) * DM + colbase;
        #pragma unroll
        for (int ds = 0; ds < 4; ++ds) {
            qfh[ds] = *(const half8*)(qhg + base + ds * 16 + hi * 8);
            qfl[ds] = *(const half8*)(qlg + base + ds * 16 + hi * 8);
        }
    }

    float m_q = -1e30f, ls = 0.0f;
    f32x16 accO0 = {};
    f32x16 accO1 = {};

    const int r0 = t >> 3;
    const int c0 = (t & 7) * 8;
    const _Float16* kph = khg + ((size_t)b * S_) * DM + colbase;
    const _Float16* kpl = klg + ((size_t)b * S_) * DM + colbase;
    const _Float16* vp  = vtg + ((size_t)b * DM + colbase) * S_;
    const unsigned char* sc0 = scanp + (b * 16 + 2 * qt) * 16;
    const unsigned char* sc1 = scanp + (b * 16 + 2 * qt + 1) * 16;

    uint4 akh0, akh1, akl0, akl1, av0, av1;
#define ALOAD(KT) do { \
        akh0 = *(const uint4*)(kph + (size_t)((KT) * 64 + r0) * DM + c0);       \
        akh1 = *(const uint4*)(kph + (size_t)((KT) * 64 + 32 + r0) * DM + c0);  \
        akl0 = *(const uint4*)(kpl + (size_t)((KT) * 64 + r0) * DM + c0);       \
        akl1 = *(const uint4*)(kpl + (size_t)((KT) * 64 + 32 + r0) * DM + c0);  \
        av0  = *(const uint4*)(vp + (size_t)r0 * S_ + (KT) * 64 + c0);          \
        av1  = *(const uint4*)(vp + (size_t)(32 + r0) * S_ + (KT) * 64 + c0);   \
    } while (0)
#define AWRITE() do { \
        *(uint4*)&Kh[r0][c0] = akh0; *(uint4*)&Kh[32 + r0][c0] = akh1; \
        *(uint4*)&Kl[r0][c0] = akl0; *(uint4*)&Kl[32 + r0][c0] = akl1; \
        *(uint4*)&Vt[r0][c0] = av0;  *(uint4*)&Vt[32 + r0][c0] = av1;  \
    } while (0)

    ALOAD(0);
    AWRITE();
    int msk = sc0[0] | sc1[0];

    const float SC = 0.125f * 1.44269504089f;   // scale * log2(e)
    const float THRRAW = 8.0f / SC;             // defer-max threshold (raw)

    for (int kt = 0; kt < 16; ++kt) {
        __syncthreads();
        const int mskcur = msk;
        if (kt < 15) {
            ALOAD(kt + 1);
            msk = sc0[kt + 1] | sc1[kt + 1];
        }

        // ---- QK^T swapped (raw scores) ----
        f32x16 sa0 = {}, sa1 = {};
        __builtin_amdgcn_s_setprio(1);
        #pragma unroll
        for (int ds = 0; ds < 4; ++ds) {
            half8 kh0 = *(const half8*)&Kh[l31][ds * 16 + hi * 8];
            half8 kl0 = *(const half8*)&Kl[l31][ds * 16 + hi * 8];
            half8 kh1 = *(const half8*)&Kh[32 + l31][ds * 16 + hi * 8];
            half8 kl1 = *(const half8*)&Kl[32 + l31][ds * 16 + hi * 8];
            sa0 = __builtin_amdgcn_mfma_f32_32x32x16_f16(kh0, qfh[ds], sa0, 0, 0, 0);
            sa0 = __builtin_amdgcn_mfma_f32_32x32x16_f16(kh0, qfl[ds], sa0, 0, 0, 0);
            sa0 = __builtin_amdgcn_mfma_f32_32x32x16_f16(kl0, qfh[ds], sa0, 0, 0, 0);
            sa1 = __builtin_amdgcn_mfma_f32_32x32x16_f16(kh1, qfh[ds], sa1, 0, 0, 0);
            sa1 = __builtin_amdgcn_mfma_f32_32x32x16_f16(kh1, qfl[ds], sa1, 0, 0, 0);
            sa1 = __builtin_amdgcn_mfma_f32_32x32x16_f16(kl1, qfh[ds], sa1, 0, 0, 0);
        }
        __builtin_amdgcn_s_setprio(0);

        if (mskcur) {   // rare path
            const unsigned char* mrow = maskg + ((size_t)b * S_ + qrow) * S_ + kt * 64;
            #pragma unroll
            for (int e = 0; e < 16; ++e) {
                int kl_ = (e & 3) + 8 * (e >> 2) + 4 * hi;
                if (mrow[kl_]) sa0[e] = -1e9f;
                if (mrow[32 + kl_]) sa1[e] = -1e9f;
            }
        }

        // ---- online softmax, raw domain, q lane-local ----
        float rm = sa0[0];
        #pragma unroll
        for (int e = 1; e < 16; ++e) rm = fmaxf(rm, sa0[e]);
        #pragma unroll
        for (int e = 0; e < 16; ++e) rm = fmaxf(rm, sa1[e]);
        rm = fmaxf(rm, __shfl_xor(rm, 32));
        if (__any(rm > m_q + THRRAW)) {          // T13: rescale only when needed
            const float mn = fmaxf(m_q, rm);
            const float sfac = exp2f((m_q - mn) * SC);
            m_q = mn;
            ls *= sfac;
            #pragma unroll
            for (int e = 0; e < 16; ++e) { accO0[e] *= sfac; accO1[e] *= sfac; }
        }
        const float nmn = -m_q * SC;
        float rs = 0.0f;
        #pragma unroll
        for (int e = 0; e < 16; ++e) { sa0[e] = exp2f(fmaf(sa0[e], SC, nmn)); rs += sa0[e]; }
        #pragma unroll
        for (int e = 0; e < 16; ++e) { sa1[e] = exp2f(fmaf(sa1[e], SC, nmn)); rs += sa1[e]; }
        rs += __shfl_xor(rs, 32);
        ls += rs;

        // ---- P -> A-frags (cvt_pkrtz + permlane32_swap), then PV ----
        half8 pf[4];
        {
            uint c0_ = pkrtz(sa0[0], sa0[1]),  c1_ = pkrtz(sa0[2], sa0[3]);
            uint c2_ = pkrtz(sa0[4], sa0[5]),  c3_ = pkrtz(sa0[6], sa0[7]);
            uint c4_ = pkrtz(sa0[8], sa0[9]),  c5_ = pkrtz(sa0[10], sa0[11]);
            uint c6_ = pkrtz(sa0[12], sa0[13]), c7_ = pkrtz(sa0[14], sa0[15]);
            PSWAP(c0_, c2_); PSWAP(c1_, c3_);
            PSWAP(c4_, c6_); PSWAP(c5_, c7_);
            uint4 u0 = {c0_, c1_, c2_, c3_}, u1 = {c4_, c5_, c6_, c7_};
            pf[0] = __builtin_bit_cast(half8, u0);
            pf[1] = __builtin_bit_cast(half8, u1);
        }
        {
            uint c0_ = pkrtz(sa1[0], sa1[1]),  c1_ = pkrtz(sa1[2], sa1[3]);
            uint c2_ = pkrtz(sa1[4], sa1[5]),  c3_ = pkrtz(sa1[6], sa1[7]);
            uint c4_ = pkrtz(sa1[8], sa1[9]),  c5_ = pkrtz(sa1[10], sa1[11]);
            uint c6_ = pkrtz(sa1[12], sa1[13]), c7_ = pkrtz(sa1[14], sa1[15]);
            PSWAP(c0_, c2_); PSWAP(c1_, c3_);
            PSWAP(c4_, c6_); PSWAP(c5_, c7_);
            uint4 u0 = {c0_, c1_, c2_, c3_}, u1 = {c4_, c5_, c6_, c7_};
            pf[2] = __builtin_bit_cast(half8, u0);
            pf[3] = __builtin_bit_cast(half8, u1);
        }
        __builtin_amdgcn_s_setprio(1);
        #pragma unroll
        for (int kc = 0; kc < 4; ++kc) {
            half8 vf0 = *(const half8*)&Vt[l31][kc * 16 + hi * 8];
            half8 vf1 = *(const half8*)&Vt[32 + l31][kc * 16 + hi * 8];
            accO0 = __builtin_amdgcn_mfma_f32_32x32x16_f16(vf0, pf[kc], accO0, 0, 0, 0);
            accO1 = __builtin_amdgcn_mfma_f32_32x32x16_f16(vf1, pf[kc], accO1, 0, 0, 0);
        }
        __builtin_amdgcn_s_setprio(0);

        __syncthreads();
        if (kt < 15) AWRITE();
    }
#undef ALOAD
#undef AWRITE

    const float inv = 1.0f / ls;
    _Float16* orow = ho + ((size_t)b * S_ + qrow) * DM + colbase;
    #pragma unroll
    for (int g2 = 0; g2 < 4; ++g2) {
        half4 hv0, hv1;
        #pragma unroll
        for (int e = 0; e < 4; ++e) {
            hv0[e] = (_Float16)(accO0[g2 * 4 + e] * inv);
            hv1[e] = (_Float16)(accO1[g2 * 4 + e] * inv);
        }
        *(half4*)(orow + g2 * 8 + hi * 4) = hv0;
        *(half4*)(orow + 32 + g2 * 8 + hi * 4) = hv1;
    }
}

// ---------------------------------------------------------------------------
extern "C" void kernel_launch(void* const* d_in, const int* in_sizes, int n_in,
                              void* d_out, int out_size, void* d_ws, size_t ws_size,
                              hipStream_t stream)
{
    const float* Qs = (const float*)d_in[0];
    const float* Ks = (const float*)d_in[1];
    const float* Vs = (const float*)d_in[2];
    const unsigned char* mask = (const unsigned char*)d_in[3];
    const float* WQ = (const float*)d_in[4];
    const float* WK = (const float*)d_in[5];
    const float* WV = (const float*)d_in[6];
    const float* WO = (const float*)d_in[7];
    const float* bo = (const float*)d_in[8];

    char* ws = (char*)d_ws;
    const size_t MB = 1024 * 1024;
    _Float16* wqh = (_Float16*)(ws + 0 * MB);
    _Float16* wql = (_Float16*)(ws + 2 * MB);
    _Float16* wkh = (_Float16*)(ws + 4 * MB);
    _Float16* wkl = (_Float16*)(ws + 6 * MB);
    _Float16* wv  = (_Float16*)(ws + 8 * MB);
    _Float16* wo  = (_Float16*)(ws + 10 * MB);
    _Float16* qhi = (_Float16*)(ws + 12 * MB);
    _Float16* qlo = (_Float16*)(ws + 28 * MB);
    _Float16* khi = (_Float16*)(ws + 44 * MB);
    _Float16* klo = (_Float16*)(ws + 60 * MB);
    _Float16* vt  = (_Float16*)(ws + 76 * MB);
    _Float16* hh  = (_Float16*)(ws + 92 * MB);
    unsigned char* scan = (unsigned char*)(ws + 108 * MB);

    packw_k<<<dim3(16, 16), 256, 0, stream>>>(WQ, WK, WV, wqh, wql, wkh, wkl, wv);
    packo_k<<<512, 256, 0, stream>>>(WO, wo);
    scan_k<<<dim3(16, 16, 8), 256, 0, stream>>>(mask, scan);

    gemm_split_k<<<dim3(8, 64, 2), 512, 0, stream>>>(
        Qs, Ks, wqh, wql, wkh, wkl, qhi, qlo, khi, klo);

    gemm_v_k<<<dim3(8, 64), 256, 0, stream>>>(Vs, wv, vt);

    attn_k<<<dim3(8, 16, 8), 256, 0, stream>>>(qhi, qlo, khi, klo, vt, mask, scan, hh);

    gemm_out_k<<<dim3(8, 64), 256, 0, stream>>>(hh, wo, (float*)d_out, bo);
}